// Round 2
// baseline (194.720 us; speedup 1.0000x reference)
//
#include <hip/hip_runtime.h>
#include <hip/hip_bf16.h>

typedef unsigned short u16;
typedef unsigned int u32;
typedef __attribute__((ext_vector_type(8))) short short8;
typedef __attribute__((ext_vector_type(4))) float floatx4;

#define BATCH 16
#define CDIM 512
#define NSPAT 1024
#define NGROUP 8

__device__ __forceinline__ u16 f2bf(float f) {
    unsigned u = __float_as_uint(f);
    u += 0x7FFFu + ((u >> 16) & 1u);   // RNE
    return (u16)(u >> 16);
}
__device__ __forceinline__ u32 f2bf2(float lo, float hi) {   // packed v_cvt_pk_bf16_f32
    __hip_bfloat162 h = __float22bfloat162_rn(make_float2(lo, hi));
    return *(u32*)&h;
}

__device__ __forceinline__ void load_lds16(const void* g, void* l) {
    __builtin_amdgcn_global_load_lds(
        (const __attribute__((address_space(1))) unsigned int*)g,
        (__attribute__((address_space(3))) unsigned int*)l, 16, 0, 0);
}

// ================= D1 prep =================
__global__ __launch_bounds__(256) void prep_kernel(
    const float* __restrict__ w_qkv, const float* __restrict__ w_proj,
    const float* __restrict__ b_qkv, const float* __restrict__ x,
    u16* __restrict__ wmega, u16* __restrict__ wproj_bf, u16* __restrict__ wv_t,
    float* __restrict__ stats, float* __restrict__ lsums, float* __restrict__ bpv) {
    int b = blockIdx.x;
    int tid = threadIdx.x;
    if (b < 768) {
        const float* src = (b < 512) ? w_qkv : w_proj;
        u16* dst = (b < 512) ? wmega : wproj_bf;
        int i = (b < 512 ? b : b - 512) * 256 + tid;
        float4 v = ((const float4*)src)[i];
        u32* d = (u32*)dst;
        d[i * 2] = f2bf2(v.x, v.y);
        d[i * 2 + 1] = f2bf2(v.z, v.w);
        return;
    }
    if (b < 832) {  // transpose w_v (rows 1024..1535 of w_qkv) -> wv_t[ci][m], 64x64 tiles
        __shared__ u16 t[64 * 66];
        int bt = b - 768;
        int tx = bt & 7, ty = bt >> 3;
        const float* src = w_qkv + (size_t)(1024 + ty * 64) * CDIM + tx * 64;
#pragma unroll
        for (int p = 0; p < 4; ++p) {
            int r = p * 16 + (tid >> 4);
            int c4 = (tid & 15) << 2;
            float4 v = *(const float4*)(src + (size_t)r * CDIM + c4);
            u16* d = &t[r * 66 + c4];
            d[0] = f2bf(v.x); d[1] = f2bf(v.y); d[2] = f2bf(v.z); d[3] = f2bf(v.w);
        }
        __syncthreads();
        u16* dst = wv_t + (size_t)(tx * 64) * CDIM + ty * 64;
#pragma unroll
        for (int p = 0; p < 4; ++p) {
            int c = p * 16 + (tid >> 4);
            int r4 = (tid & 15) << 2;
            ushort4 o;
            o.x = t[(r4 + 0) * 66 + c];
            o.y = t[(r4 + 1) * 66 + c];
            o.z = t[(r4 + 2) * 66 + c];
            o.w = t[(r4 + 3) * 66 + c];
            *(ushort4*)(dst + (size_t)c * CDIM + r4) = o;
        }
        return;
    }
    if (b < 960) {  // stats
        __shared__ float rs[4], rss[4];
        int bg = b - 832;
        const float4* xv = (const float4*)(x + (size_t)bg * 65536);
        float s = 0.f, ss = 0.f;
        for (int i = tid; i < 16384; i += 256) {
            float4 v = xv[i];
            s += v.x + v.y + v.z + v.w;
            ss += v.x * v.x + v.y * v.y + v.z * v.z + v.w * v.w;
        }
#pragma unroll
        for (int off = 32; off; off >>= 1) { s += __shfl_down(s, off); ss += __shfl_down(ss, off); }
        int wave = tid >> 6, lane = tid & 63;
        if (lane == 0) { rs[wave] = s; rss[wave] = ss; }
        __syncthreads();
        if (tid == 0) {
            float S1 = rs[0] + rs[1] + rs[2] + rs[3];
            float S2 = rss[0] + rss[1] + rss[2] + rss[3];
            float mean = S1 * (1.f / 65536.f);
            float var = S2 * (1.f / 65536.f) - mean * mean;
            stats[bg * 2] = mean;
            stats[bg * 2 + 1] = rsqrtf(var + 1e-5f);
        }
        return;
    }
    if (b < 976) {  // zero lsums
        ((float4*)lsums)[(b - 960) * 256 + tid] = (float4){0.f, 0.f, 0.f, 0.f};
        return;
    }
    {   // bpv
        int o0 = (b - 976) * 64;
        int wave = tid >> 6, lane = tid & 63;
        const float4* bvv = (const float4*)(b_qkv + 1024);
        float4 v0 = bvv[lane * 2], v1 = bvv[lane * 2 + 1];
        for (int it = 0; it < 16; ++it) {
            int o = o0 + wave * 16 + it;
            const float4* wr = (const float4*)(w_proj + (size_t)o * CDIM);
            float4 a0 = wr[lane * 2], a1 = wr[lane * 2 + 1];
            float s = a0.x * v0.x + a0.y * v0.y + a0.z * v0.z + a0.w * v0.w
                    + a1.x * v1.x + a1.y * v1.y + a1.z * v1.z + a1.w * v1.w;
#pragma unroll
            for (int off = 32; off; off >>= 1) s += __shfl_down(s, off);
            if (lane == 0) bpv[o] = s;
        }
    }
}

// ================= legacy single-buffer 128x128x64 core (Wpv only) =================
__device__ __forceinline__ void stage_tile(
    const u16* __restrict__ Ab, const u16* __restrict__ Bb, int lda, int ldb,
    int m0, int n0, int k0, u16* As, u16* Bs) {
    int tid = threadIdx.x;
#pragma unroll
    for (int it = 0; it < 4; ++it) {
        int c = it * 256 + tid;
        int r = c >> 3, p = c & 7;
        int kc = p ^ (r & 7);               // slot p holds global chunk p^(r&7)
        load_lds16(Ab + (size_t)(m0 + r) * lda + k0 + (kc << 3), &As[c << 3]);
        load_lds16(Bb + (size_t)(n0 + r) * ldb + k0 + (kc << 3), &Bs[c << 3]);
    }
}

__device__ __forceinline__ void compute_tile(
    const u16* As, const u16* Bs, int wm, int wn, int quad, int lrow,
    floatx4 (&acc)[4][4]) {
#pragma unroll
    for (int s = 0; s < 2; ++s) {
        short8 af[4], bf[4];
#pragma unroll
        for (int i = 0; i < 4; ++i) {
            int R = wm + i * 16 + lrow;
            int p = (s * 4 + quad) ^ (R & 7);
            af[i] = *(const short8*)&As[(R << 6) + (p << 3)];
        }
#pragma unroll
        for (int j = 0; j < 4; ++j) {
            int R = wn + j * 16 + lrow;
            int p = (s * 4 + quad) ^ (R & 7);
            bf[j] = *(const short8*)&Bs[(R << 6) + (p << 3)];
        }
#pragma unroll
        for (int i = 0; i < 4; ++i)
#pragma unroll
            for (int j = 0; j < 4; ++j)
                acc[i][j] = __builtin_amdgcn_mfma_f32_16x16x32_bf16(af[i], bf[j], acc[i][j], 0, 0, 0);
    }
}

__device__ __forceinline__ void gemm_core_sb(
    const u16* __restrict__ Ab, const u16* __restrict__ Bb, int K, int lda, int ldb,
    int m0, int n0, u16* As, u16* Bs, floatx4 (&acc)[4][4]) {
    int tid = threadIdx.x;
    int lane = tid & 63, wave = tid >> 6, quad = lane >> 4, lrow = lane & 15;
    int wm = (wave >> 1) << 6, wn = (wave & 1) << 6;
    for (int k0 = 0; k0 < K; k0 += 64) {
        stage_tile(Ab, Bb, lda, ldb, m0, n0, k0, As, Bs);
        __syncthreads();
        compute_tile(As, Bs, wm, wn, quad, lrow, acc);
        __syncthreads();
    }
}

// ================= reg-A + LDS-B double-buffered core =================
// A fragments loaded straight from global into VGPRs (no LDS round-trip,
// layout is the natural MFMA fragment address). B staged via global_load_lds
// into a 2x16KB XOR-swizzled double buffer. Counted vmcnt(12) = 4 B-stage +
// 8 A-frag loads of the NEXT tile stay in flight across the barrier.
__device__ __forceinline__ void stage_B(
    const u16* __restrict__ Bb, int ldb, int n0, int k0, u16* Bs) {
    int tid = threadIdx.x;
#pragma unroll
    for (int it = 0; it < 4; ++it) {
        int c = it * 256 + tid;
        int r = c >> 3, p = c & 7;
        int kc = p ^ (r & 7);               // slot p holds global chunk p^(r&7)
        load_lds16(Bb + (size_t)(n0 + r) * ldb + k0 + (kc << 3), &Bs[c << 3]);
    }
}

#define LOAD_AFRAG(dst, base, lda, k0) \
    _Pragma("unroll") for (int i_ = 0; i_ < 4; ++i_) \
    _Pragma("unroll") for (int s_ = 0; s_ < 2; ++s_) \
        dst[s_ * 4 + i_] = *(const short8*)((base) + (size_t)i_ * 16 * (lda) + (k0) + s_ * 32);

__device__ __forceinline__ void compute_ra(
    const short8 (&af)[8], const u16* Bs, int wn, int quad, int lrow,
    floatx4 (&acc)[4][4]) {
#pragma unroll
    for (int s = 0; s < 2; ++s) {
        short8 bf[4];
#pragma unroll
        for (int j = 0; j < 4; ++j) {
            int R = wn + j * 16 + lrow;
            int p = (s * 4 + quad) ^ (R & 7);
            bf[j] = *(const short8*)&Bs[(R << 6) + (p << 3)];
        }
#pragma unroll
        for (int i = 0; i < 4; ++i)
#pragma unroll
            for (int j = 0; j < 4; ++j)
                acc[i][j] = __builtin_amdgcn_mfma_f32_16x16x32_bf16(af[s * 4 + i], bf[j], acc[i][j], 0, 0, 0);
    }
}

__device__ __forceinline__ void gemm_core_ra(
    const u16* __restrict__ Ab, const u16* __restrict__ Bb, int K, int lda, int ldb,
    int m0, int n0, u16* Bs, floatx4 (&acc)[4][4]) {
    int tid = threadIdx.x;
    int lane = tid & 63, wave = tid >> 6, quad = lane >> 4, lrow = lane & 15;
    int wn = (wave & 1) << 6;
    int wm = (wave >> 1) << 6;
    const u16* ap = Ab + (size_t)(m0 + wm + lrow) * lda + (quad << 3);
    const int TS = 128 * 64;
    int nt = K >> 6;
    short8 afc[8], afn[8];
    stage_B(Bb, ldb, n0, 0, Bs);                       // 4 loads/thread in flight
    LOAD_AFRAG(afc, ap, lda, 0);                       // +8 -> 12 in flight
    u16 *Bc = Bs, *Bn = Bs + TS;
    for (int t = 0; t < nt - 1; ++t) {
        stage_B(Bb, ldb, n0, (t + 1) << 6, Bn);        // +4
        LOAD_AFRAG(afn, ap, lda, (t + 1) << 6);        // +8  (12 new in flight)
        asm volatile("s_waitcnt vmcnt(12)" ::: "memory");   // tile-t's 12 done
        __builtin_amdgcn_s_barrier();                  // all waves see B(t) in LDS
        __builtin_amdgcn_sched_barrier(0);             // keep ds_reads below barrier
        compute_ra(afc, Bc, wn, quad, lrow, acc);
        __builtin_amdgcn_sched_barrier(0);             // keep reads above barrier
        __builtin_amdgcn_s_barrier();                  // B(t) buffer reusable
#pragma unroll
        for (int i = 0; i < 8; ++i) afc[i] = afn[i];
        u16* tb = Bc; Bc = Bn; Bn = tb;
    }
    asm volatile("s_waitcnt vmcnt(0)" ::: "memory");
    __builtin_amdgcn_s_barrier();
    __builtin_amdgcn_sched_barrier(0);
    compute_ra(afc, Bc, wn, quad, lrow, acc);
}

#define ACC_INIT floatx4 acc[4][4]; \
    _Pragma("unroll") for (int i = 0; i < 4; ++i) \
    _Pragma("unroll") for (int j = 0; j < 4; ++j) acc[i][j] = (floatx4){0.f, 0.f, 0.f, 0.f};

#define EPILOG_IDX int lane = threadIdx.x & 63, wave = threadIdx.x >> 6; \
    int quad = lane >> 4, lrow = lane & 15; \
    int wm = (wave >> 1) << 6, wn = (wave & 1) << 6;

// ================= D2: GN apply+transpose (z<16) + Wpv GEMM (z==16) =================
#define TSTR 66
__global__ __launch_bounds__(256) void gn_wpv_kernel(
    const float* __restrict__ x, const float* __restrict__ gamma, const float* __restrict__ beta,
    const float* __restrict__ stats, u16* __restrict__ hT,
    const u16* __restrict__ wproj_bf, const u16* __restrict__ wv_t, u16* __restrict__ wmega) {
    __shared__ u16 smem[2 * 128 * 64];
    int tid = threadIdx.x;
    if (blockIdx.z == 16) {  // Wpv = wproj_bf . wv_t^T -> wmega rows 1024..1535
        if (blockIdx.x >= 4 || blockIdx.y >= 4) return;
        int m0 = blockIdx.y << 7, n0 = blockIdx.x << 7;
        ACC_INIT;
        gemm_core_sb(wproj_bf, wv_t, CDIM, CDIM, CDIM, m0, n0, smem, smem + 128 * 64, acc);
        EPILOG_IDX;
#pragma unroll
        for (int i = 0; i < 4; ++i)
#pragma unroll
            for (int j = 0; j < 4; ++j)
#pragma unroll
                for (int r = 0; r < 4; ++r) {
                    int R = m0 + wm + i * 16 + (quad << 2) + r;
                    int Cc = n0 + wn + j * 16 + lrow;
                    wmega[(size_t)(1024 + R) * CDIM + Cc] = f2bf(acc[i][j][r]);
                }
        return;
    }
    u16* t = smem;
    int b = blockIdx.z, c0 = blockIdx.y << 6, n0 = blockIdx.x << 6;
    const float* xb = x + ((size_t)b * CDIM + c0) * NSPAT + n0;
#pragma unroll
    for (int p = 0; p < 4; ++p) {
        int cl = p * 16 + (tid >> 4);
        int nl = (tid & 15) << 2;
        int c = c0 + cl;
        int bg = b * NGROUP + (c >> 6);
        float ga = gamma[c] * stats[bg * 2 + 1];
        float be = beta[c] - stats[bg * 2] * ga;
        float4 v = *(const float4*)(xb + (size_t)cl * NSPAT + nl);
        u16* dst = &t[cl * TSTR + nl];
        dst[0] = f2bf(v.x * ga + be);
        dst[1] = f2bf(v.y * ga + be);
        dst[2] = f2bf(v.z * ga + be);
        dst[3] = f2bf(v.w * ga + be);
    }
    __syncthreads();
    u16* hb = hT + ((size_t)b * NSPAT + n0) * CDIM + c0;
#pragma unroll
    for (int p = 0; p < 4; ++p) {
        int nl = p * 16 + (tid >> 4);
        int cl4 = (tid & 15) << 2;
        ushort4 o;
        o.x = t[(cl4 + 0) * TSTR + nl];
        o.y = t[(cl4 + 1) * TSTR + nl];
        o.z = t[(cl4 + 2) * TSTR + nl];
        o.w = t[(cl4 + 3) * TSTR + nl];
        *(ushort4*)(hb + (size_t)nl * CDIM + cl4) = o;
    }
}

// ================= D3: qkv-mega: [q;k;WV] = wmega . h + [b_qkv(qk); bpv] =================
// grid (BATCH, 8, 12): batch in x for XCD affinity.
__global__ __launch_bounds__(256) void qkv_kernel(
    const u16* __restrict__ wmega, const u16* __restrict__ hT,
    const float* __restrict__ b_qkv, const float* __restrict__ bpv,
    u16* __restrict__ qkT, u16* __restrict__ WV) {
    __shared__ u16 Bs[2 * 128 * 64];
    int z = blockIdx.x;
    int n0 = blockIdx.y << 7;
    int m0 = blockIdx.z << 7;
    const u16* Bb = hT + (size_t)z * CDIM * NSPAT;
    ACC_INIT;
    gemm_core_ra(wmega, Bb, CDIM, CDIM, CDIM, m0, n0, Bs, acc);
    EPILOG_IDX;
    if (blockIdx.z < 8) {  // q,k rows: transposed packed store to qkT[n][o], ldc=1024
        u16* qk = qkT + (size_t)z * NSPAT * NSPAT;
#pragma unroll
        for (int i = 0; i < 4; ++i)
#pragma unroll
            for (int j = 0; j < 4; ++j) {
                int R0 = m0 + wm + i * 16 + (quad << 2);
                int Cc = n0 + wn + j * 16 + lrow;
                uint2 u;
                u.x = f2bf2(acc[i][j][0] + b_qkv[R0 + 0], acc[i][j][1] + b_qkv[R0 + 1]);
                u.y = f2bf2(acc[i][j][2] + b_qkv[R0 + 2], acc[i][j][3] + b_qkv[R0 + 3]);
                *(uint2*)&qk[(size_t)Cc * NSPAT + R0] = u;
            }
    } else {  // WV rows: natural store WV[o][n] + bpv
        u16* Wp = WV + (size_t)z * CDIM * NSPAT;
#pragma unroll
        for (int i = 0; i < 4; ++i)
#pragma unroll
            for (int j = 0; j < 4; ++j)
#pragma unroll
                for (int r = 0; r < 4; ++r) {
                    int R = m0 - 1024 + wm + i * 16 + (quad << 2) + r;
                    int Cc = n0 + wn + j * 16 + lrow;
                    Wp[(size_t)R * NSPAT + Cc] = f2bf(acc[i][j][r] + bpv[R]);
                }
    }
}

// ================= D4: scores (swapped operands): D[j][i] = k_j . q_i =================
// grid (BATCH, 8, 8): y = i-tile, z = j-tile.
__global__ __launch_bounds__(256) void scores_kernel(
    const u16* __restrict__ qkT, u16* __restrict__ P, float* __restrict__ lsums, float scale) {
    __shared__ u16 Bs[2 * 128 * 64];
    int z = blockIdx.x;
    int n0 = blockIdx.y << 7;                // i tile (N-dim)
    int m0 = blockIdx.z << 7;                // j tile (M-dim)
    const u16* qb = qkT + (size_t)z * NSPAT * NSPAT;
    ACC_INIT;
    gemm_core_ra(qb + CDIM, qb, CDIM, NSPAT, NSPAT, m0, n0, Bs, acc);
    EPILOG_IDX;
    u16* Pp = P + (size_t)z * NSPAT * NSPAT;
    float* ls = lsums + (size_t)z * NSPAT;
#pragma unroll
    for (int nj = 0; nj < 4; ++nj) {
        int Ci = n0 + wn + nj * 16 + lrow;       // i (column of D)
        float part = 0.f;
#pragma unroll
        for (int mi = 0; mi < 4; ++mi) {
            int Rj0 = m0 + wm + mi * 16 + (quad << 2);   // j (rows of D), 4 consecutive
            float e0 = __expf(acc[mi][nj][0] * scale);
            float e1 = __expf(acc[mi][nj][1] * scale);
            float e2 = __expf(acc[mi][nj][2] * scale);
            float e3 = __expf(acc[mi][nj][3] * scale);
            part += (e0 + e1) + (e2 + e3);
            uint2 u;
            u.x = f2bf2(e0, e1);
            u.y = f2bf2(e2, e3);
            *(uint2*)&Pp[(size_t)Ci * NSPAT + Rj0] = u;
        }
        part += __shfl_xor(part, 16);
        part += __shfl_xor(part, 32);
        if (lane < 16) atomicAdd(&ls[Ci], part);
    }
}

// ================= D5: final (swapped operands): D[i][o] = P_i . WV_o =================
// grid (BATCH, 4, 8): y = o-tile, z = i-tile.
__global__ __launch_bounds__(256) void final_kernel(
    const u16* __restrict__ WV, const u16* __restrict__ P, const float* __restrict__ lsums,
    const float* __restrict__ bias, const float* __restrict__ x, float* __restrict__ out) {
    __shared__ u16 Bs[2 * 128 * 64];
    int z = blockIdx.x;
    int n0 = blockIdx.y << 7;                // o tile (N-dim, 4 tiles)
    int m0 = blockIdx.z << 7;                // i tile (M-dim, 8 tiles)
    const u16* Pb = P + (size_t)z * NSPAT * NSPAT;
    const u16* WVb = WV + (size_t)z * CDIM * NSPAT;
    ACC_INIT;
    gemm_core_ra(Pb, WVb, NSPAT, NSPAT, NSPAT, m0, n0, Bs, acc);
    EPILOG_IDX;
    float* Op = out + (size_t)z * CDIM * NSPAT;
    const float* xr = x + (size_t)z * CDIM * NSPAT;
    const float* li = lsums + (size_t)z * NSPAT;
#pragma unroll
    for (int mi = 0; mi < 4; ++mi) {
        int Ri0 = m0 + wm + mi * 16 + (quad << 2);       // i, 4 consecutive
        float4 lv = *(const float4*)&li[Ri0];
        float s0 = __builtin_amdgcn_rcpf(lv.x);
        float s1 = __builtin_amdgcn_rcpf(lv.y);
        float s2 = __builtin_amdgcn_rcpf(lv.z);
        float s3 = __builtin_amdgcn_rcpf(lv.w);
#pragma unroll
        for (int nj = 0; nj < 4; ++nj) {
            int Co = n0 + wn + nj * 16 + lrow;           // o
            float bv = bias[Co];
            size_t off = (size_t)Co * NSPAT + Ri0;
            float4 xv = *(const float4*)&xr[off];
            float4 o;
            o.x = acc[mi][nj][0] * s0 + bv + xv.x;
            o.y = acc[mi][nj][1] * s1 + bv + xv.y;
            o.z = acc[mi][nj][2] * s2 + bv + xv.z;
            o.w = acc[mi][nj][3] * s3 + bv + xv.w;
            *(float4*)&Op[off] = o;
        }
    }
}

// ================= launch =================
extern "C" void kernel_launch(void* const* d_in, const int* in_sizes, int n_in,
                              void* d_out, int out_size, void* d_ws, size_t ws_size,
                              hipStream_t stream) {
    const float* x      = (const float*)d_in[0];
    const float* gamma  = (const float*)d_in[1];
    const float* beta   = (const float*)d_in[2];
    const float* w_qkv  = (const float*)d_in[3];
    const float* b_qkv  = (const float*)d_in[4];
    const float* w_proj = (const float*)d_in[5];
    const float* b_proj = (const float*)d_in[6];
    float* out = (float*)d_out;

    const size_t CN = (size_t)CDIM * NSPAT;   // 524288
    const size_t NN = (size_t)NSPAT * NSPAT;  // 1048576
    const float SCALE = 0.044194173824159216f;

    char* ws = (char*)d_ws;
    float* stats   = (float*)ws;                              // 1 KB
    float* bpv     = (float*)(ws + 1024);                     // 2 KB
    u16* wmega     = (u16*)(ws + 4096);                       // [Wq;Wk;Wpv] 1536x512 bf16
    u16* wproj_bf  = wmega + (size_t)3 * CDIM * CDIM;         // 0.5 MB
    u16* wv_t      = wproj_bf + (size_t)CDIM * CDIM;          // 0.5 MB
    u16* hT        = wv_t + (size_t)CDIM * CDIM;              // 16.8 MB [n][c]
    u16* qkT       = hT + BATCH * CN;                         // 33.5 MB [n][q,k:1024]
    u16* WV        = qkT + BATCH * NN;                        // 16.8 MB [o][n]
    u16* P         = WV + BATCH * CN;                         // 33.5 MB [i][j] unnorm
    float* lsums   = (float*)(P + BATCH * NN);                // 64 KB

    prep_kernel<<<984, 256, 0, stream>>>(
        w_qkv, w_proj, b_qkv, x, wmega, wproj_bf, wv_t, stats, lsums, bpv);

    gn_wpv_kernel<<<dim3(16, 8, 17), 256, 0, stream>>>(
        x, gamma, beta, stats, hT, wproj_bf, wv_t, wmega);

    qkv_kernel<<<dim3(BATCH, 8, 12), 256, 0, stream>>>(
        wmega, hT, b_qkv, bpv, qkT, WV);

    scores_kernel<<<dim3(BATCH, 8, 8), 256, 0, stream>>>(qkT, P, lsums, SCALE);

    final_kernel<<<dim3(BATCH, 4, 8), 256, 0, stream>>>(WV, P, lsums, b_proj, x, out);
}

// Round 3
// 149.898 us; speedup vs baseline: 1.2990x; 1.2990x over previous
//
#include <hip/hip_runtime.h>
#include <hip/hip_bf16.h>

typedef unsigned short u16;
typedef unsigned int u32;
typedef __attribute__((ext_vector_type(8))) short short8;
typedef __attribute__((ext_vector_type(4))) float floatx4;

#define BATCH 16
#define CDIM 512
#define NSPAT 1024
#define NGROUP 8

__device__ __forceinline__ u16 f2bf(float f) {
    unsigned u = __float_as_uint(f);
    u += 0x7FFFu + ((u >> 16) & 1u);   // RNE
    return (u16)(u >> 16);
}
__device__ __forceinline__ u32 f2bf2(float lo, float hi) {   // packed v_cvt_pk_bf16_f32
    __hip_bfloat162 h = __float22bfloat162_rn(make_float2(lo, hi));
    return *(u32*)&h;
}

__device__ __forceinline__ void load_lds16(const void* g, void* l) {
    __builtin_amdgcn_global_load_lds(
        (const __attribute__((address_space(1))) unsigned int*)g,
        (__attribute__((address_space(3))) unsigned int*)l, 16, 0, 0);
}

// ================= D1 prep =================
__global__ __launch_bounds__(256) void prep_kernel(
    const float* __restrict__ w_qkv, const float* __restrict__ w_proj,
    const float* __restrict__ b_qkv, const float* __restrict__ x,
    u16* __restrict__ wmega, u16* __restrict__ wproj_bf, u16* __restrict__ wv_t,
    float* __restrict__ stats, float* __restrict__ lsums, float* __restrict__ bpv) {
    int b = blockIdx.x;
    int tid = threadIdx.x;
    if (b < 768) {
        const float* src = (b < 512) ? w_qkv : w_proj;
        u16* dst = (b < 512) ? wmega : wproj_bf;
        int i = (b < 512 ? b : b - 512) * 256 + tid;
        float4 v = ((const float4*)src)[i];
        u32* d = (u32*)dst;
        d[i * 2] = f2bf2(v.x, v.y);
        d[i * 2 + 1] = f2bf2(v.z, v.w);
        return;
    }
    if (b < 832) {  // transpose w_v (rows 1024..1535 of w_qkv) -> wv_t[ci][m], 64x64 tiles
        __shared__ u16 t[64 * 66];
        int bt = b - 768;
        int tx = bt & 7, ty = bt >> 3;
        const float* src = w_qkv + (size_t)(1024 + ty * 64) * CDIM + tx * 64;
#pragma unroll
        for (int p = 0; p < 4; ++p) {
            int r = p * 16 + (tid >> 4);
            int c4 = (tid & 15) << 2;
            float4 v = *(const float4*)(src + (size_t)r * CDIM + c4);
            u16* d = &t[r * 66 + c4];
            d[0] = f2bf(v.x); d[1] = f2bf(v.y); d[2] = f2bf(v.z); d[3] = f2bf(v.w);
        }
        __syncthreads();
        u16* dst = wv_t + (size_t)(tx * 64) * CDIM + ty * 64;
#pragma unroll
        for (int p = 0; p < 4; ++p) {
            int c = p * 16 + (tid >> 4);
            int r4 = (tid & 15) << 2;
            ushort4 o;
            o.x = t[(r4 + 0) * 66 + c];
            o.y = t[(r4 + 1) * 66 + c];
            o.z = t[(r4 + 2) * 66 + c];
            o.w = t[(r4 + 3) * 66 + c];
            *(ushort4*)(dst + (size_t)c * CDIM + r4) = o;
        }
        return;
    }
    if (b < 960) {  // stats
        __shared__ float rs[4], rss[4];
        int bg = b - 832;
        const float4* xv = (const float4*)(x + (size_t)bg * 65536);
        float s = 0.f, ss = 0.f;
        for (int i = tid; i < 16384; i += 256) {
            float4 v = xv[i];
            s += v.x + v.y + v.z + v.w;
            ss += v.x * v.x + v.y * v.y + v.z * v.z + v.w * v.w;
        }
#pragma unroll
        for (int off = 32; off; off >>= 1) { s += __shfl_down(s, off); ss += __shfl_down(ss, off); }
        int wave = tid >> 6, lane = tid & 63;
        if (lane == 0) { rs[wave] = s; rss[wave] = ss; }
        __syncthreads();
        if (tid == 0) {
            float S1 = rs[0] + rs[1] + rs[2] + rs[3];
            float S2 = rss[0] + rss[1] + rss[2] + rss[3];
            float mean = S1 * (1.f / 65536.f);
            float var = S2 * (1.f / 65536.f) - mean * mean;
            stats[bg * 2] = mean;
            stats[bg * 2 + 1] = rsqrtf(var + 1e-5f);
        }
        return;
    }
    if (b < 976) {  // zero lsums
        ((float4*)lsums)[(b - 960) * 256 + tid] = (float4){0.f, 0.f, 0.f, 0.f};
        return;
    }
    {   // bpv
        int o0 = (b - 976) * 64;
        int wave = tid >> 6, lane = tid & 63;
        const float4* bvv = (const float4*)(b_qkv + 1024);
        float4 v0 = bvv[lane * 2], v1 = bvv[lane * 2 + 1];
        for (int it = 0; it < 16; ++it) {
            int o = o0 + wave * 16 + it;
            const float4* wr = (const float4*)(w_proj + (size_t)o * CDIM);
            float4 a0 = wr[lane * 2], a1 = wr[lane * 2 + 1];
            float s = a0.x * v0.x + a0.y * v0.y + a0.z * v0.z + a0.w * v0.w
                    + a1.x * v1.x + a1.y * v1.y + a1.z * v1.z + a1.w * v1.w;
#pragma unroll
            for (int off = 32; off; off >>= 1) s += __shfl_down(s, off);
            if (lane == 0) bpv[o] = s;
        }
    }
}

// ================= legacy single-buffer 128x128x64 core (Wpv only, 256 thr) =================
__device__ __forceinline__ void stage_tile(
    const u16* __restrict__ Ab, const u16* __restrict__ Bb, int lda, int ldb,
    int m0, int n0, int k0, u16* As, u16* Bs) {
    int tid = threadIdx.x;
#pragma unroll
    for (int it = 0; it < 4; ++it) {
        int c = it * 256 + tid;
        int r = c >> 3, p = c & 7;
        int kc = p ^ (r & 7);
        load_lds16(Ab + (size_t)(m0 + r) * lda + k0 + (kc << 3), &As[c << 3]);
        load_lds16(Bb + (size_t)(n0 + r) * ldb + k0 + (kc << 3), &Bs[c << 3]);
    }
}

__device__ __forceinline__ void compute_tile(
    const u16* As, const u16* Bs, int wm, int wn, int quad, int lrow,
    floatx4 (&acc)[4][4]) {
#pragma unroll
    for (int s = 0; s < 2; ++s) {
        short8 af[4], bf[4];
#pragma unroll
        for (int i = 0; i < 4; ++i) {
            int R = wm + i * 16 + lrow;
            int p = (s * 4 + quad) ^ (R & 7);
            af[i] = *(const short8*)&As[(R << 6) + (p << 3)];
        }
#pragma unroll
        for (int j = 0; j < 4; ++j) {
            int R = wn + j * 16 + lrow;
            int p = (s * 4 + quad) ^ (R & 7);
            bf[j] = *(const short8*)&Bs[(R << 6) + (p << 3)];
        }
#pragma unroll
        for (int i = 0; i < 4; ++i)
#pragma unroll
            for (int j = 0; j < 4; ++j)
                acc[i][j] = __builtin_amdgcn_mfma_f32_16x16x32_bf16(af[i], bf[j], acc[i][j], 0, 0, 0);
    }
}

__device__ __forceinline__ void gemm_core_sb(
    const u16* __restrict__ Ab, const u16* __restrict__ Bb, int K, int lda, int ldb,
    int m0, int n0, u16* As, u16* Bs, floatx4 (&acc)[4][4]) {
    int tid = threadIdx.x;
    int lane = tid & 63, wave = tid >> 6, quad = lane >> 4, lrow = lane & 15;
    int wm = (wave >> 1) << 6, wn = (wave & 1) << 6;
    for (int k0 = 0; k0 < K; k0 += 64) {
        stage_tile(Ab, Bb, lda, ldb, m0, n0, k0, As, Bs);
        __syncthreads();
        compute_tile(As, Bs, wm, wn, quad, lrow, acc);
        __syncthreads();
    }
}

#define ACC_INIT floatx4 acc[4][4]; \
    _Pragma("unroll") for (int i = 0; i < 4; ++i) \
    _Pragma("unroll") for (int j = 0; j < 4; ++j) acc[i][j] = (floatx4){0.f, 0.f, 0.f, 0.f};

#define EPILOG_IDX int lane = threadIdx.x & 63, wave = threadIdx.x >> 6; \
    int quad = lane >> 4, lrow = lane & 15; \
    int wm = (wave >> 1) << 6, wn = (wave & 1) << 6;

// ================= 256x128x64 8-wave 4-phase pipelined core (512 thr) =================
// LDS (dynamic, 96KB): A: 2 slots x 2 halves x (128 ridx x 64 u16)   [0, 32768) u16
//                      B: 2 slots x 2 halves x ( 64 ridx x 64 u16)   [32768, 49152) u16
// A-half h = rows {wrow*128 + h*64 + 0..63}  (read only in phases qm==h)
// B-half h = rows {wcol*32  + h*16 + 0..15}  (read only in phases qn==h)
// Per K-tile: 4 phases (qm,qn) = (0,0),(0,1),(1,0),(1,1); per phase one half-tile issued:
//   P1: A1(t+1)  P2: B1(t+1)  P3: A0(t+2)  P4: B0(t+2)   (target freed by that phase's barrier)
// Boundary wait at P1(t): vmcnt(3) = A0(t+1)[2 loads]+B0(t+1)[1] allowed outstanding.
#define TSA 16384
#define TSB 8192

__device__ __forceinline__ void issueA(
    const u16* __restrict__ Ab, int lda, int m0, int t, int h, u16* smem) {
    int tid = threadIdx.x;
    u16* base = smem + (t & 1) * TSA + h * 8192;
#pragma unroll
    for (int l = 0; l < 2; ++l) {
        int c = l * 512 + tid;
        int ridx = c >> 3, p = c & 7;
        int kc = p ^ (ridx & 7);
        int r = ((ridx >> 6) << 7) + (h << 6) + (ridx & 63);
        load_lds16(Ab + (size_t)(m0 + r) * lda + (t << 6) + (kc << 3), base + (c << 3));
    }
}

__device__ __forceinline__ void issueB(
    const u16* __restrict__ Bb, int ldb, int n0, int t, int h, u16* smem) {
    int tid = threadIdx.x;
    u16* base = smem + 2 * TSA + (t & 1) * TSB + h * 4096;
    int ridx = tid >> 3, p = tid & 7;
    int kc = p ^ (ridx & 7);
    int r = ((ridx >> 4) << 5) + (h << 4) + (ridx & 15);
    load_lds16(Bb + (size_t)(n0 + r) * ldb + (t << 6) + (kc << 3), base + (tid << 3));
}

__device__ __forceinline__ void comp_phase(
    const u16* smem, int slot, int qm, int qn,
    int wrow, int wcol, int quad, int lrow, floatx4 (&acc)[8][2]) {
    const u16* Abase = smem + slot * TSA + qm * 8192;
    const u16* Bbase = smem + 2 * TSA + slot * TSB + qn * 4096;
    short8 af[8];
    short8 bf[2];
#pragma unroll
    for (int ks = 0; ks < 2; ++ks) {
#pragma unroll
        for (int i = 0; i < 4; ++i) {
            int ridx = wrow * 64 + i * 16 + lrow;
            int p = (ks * 4 + quad) ^ (ridx & 7);
            af[ks * 4 + i] = *(const short8*)&Abase[(ridx << 6) + (p << 3)];
        }
        int ridxb = wcol * 16 + lrow;
        int pb = (ks * 4 + quad) ^ (ridxb & 7);
        bf[ks] = *(const short8*)&Bbase[(ridxb << 6) + (pb << 3)];
    }
    asm volatile("s_waitcnt lgkmcnt(0)" ::: "memory");
    __builtin_amdgcn_sched_barrier(0);
    __builtin_amdgcn_s_setprio(1);
#pragma unroll
    for (int ks = 0; ks < 2; ++ks)
#pragma unroll
        for (int i = 0; i < 4; ++i)
            acc[qm * 4 + i][qn] = __builtin_amdgcn_mfma_f32_16x16x32_bf16(
                af[ks * 4 + i], bf[ks], acc[qm * 4 + i][qn], 0, 0, 0);
    __builtin_amdgcn_s_setprio(0);
}

#define PHASE_BAR  __builtin_amdgcn_s_barrier(); __builtin_amdgcn_sched_barrier(0);

__device__ __forceinline__ void gemm256(
    const u16* __restrict__ Ab, const u16* __restrict__ Bb, int K, int lda, int ldb,
    int m0, int n0, u16* smem, floatx4 (&acc)[8][2]) {
    int tid = threadIdx.x;
    int lane = tid & 63, wave = tid >> 6;
    int quad = lane >> 4, lrow = lane & 15;
    int wrow = wave >> 2, wcol = wave & 3;
    int nt = K >> 6;
    // prologue: tile0 all 4 halves, then A0/B0 of tile1  (9 loads/thread)
    issueA(Ab, lda, m0, 0, 0, smem);
    issueA(Ab, lda, m0, 0, 1, smem);
    issueB(Bb, ldb, n0, 0, 0, smem);
    issueB(Bb, ldb, n0, 0, 1, smem);
    issueA(Ab, lda, m0, 1, 0, smem);
    issueB(Bb, ldb, n0, 1, 0, smem);
    for (int t = 0; t < nt; ++t) {
        int slot = t & 1;
        // ---- P1: Q(0,0)
        if (t + 1 < nt) { asm volatile("s_waitcnt vmcnt(3)" ::: "memory"); }
        else            { asm volatile("s_waitcnt vmcnt(0)" ::: "memory"); }
        PHASE_BAR;
        if (t + 1 < nt) issueA(Ab, lda, m0, t + 1, 1, smem);
        comp_phase(smem, slot, 0, 0, wrow, wcol, quad, lrow, acc);
        // ---- P2: Q(0,1)
        PHASE_BAR;
        if (t + 1 < nt) issueB(Bb, ldb, n0, t + 1, 1, smem);
        comp_phase(smem, slot, 0, 1, wrow, wcol, quad, lrow, acc);
        // ---- P3: Q(1,0)
        PHASE_BAR;
        if (t + 2 < nt) issueA(Ab, lda, m0, t + 2, 0, smem);
        comp_phase(smem, slot, 1, 0, wrow, wcol, quad, lrow, acc);
        // ---- P4: Q(1,1)
        PHASE_BAR;
        if (t + 2 < nt) issueB(Bb, ldb, n0, t + 2, 0, smem);
        comp_phase(smem, slot, 1, 1, wrow, wcol, quad, lrow, acc);
    }
    __builtin_amdgcn_sched_barrier(0);
}

#define ACC_INIT8 floatx4 acc[8][2]; \
    _Pragma("unroll") for (int i = 0; i < 8; ++i) \
    _Pragma("unroll") for (int j = 0; j < 2; ++j) acc[i][j] = (floatx4){0.f, 0.f, 0.f, 0.f};

#define EPILOG_IDX8 int lane = threadIdx.x & 63, wave = threadIdx.x >> 6; \
    int quad = lane >> 4, lrow = lane & 15; \
    int wrow = wave >> 2, wcol = wave & 3;

// ================= D2: GN apply+transpose (z<16) + Wpv GEMM (z==16) =================
#define TSTR 66
__global__ __launch_bounds__(256) void gn_wpv_kernel(
    const float* __restrict__ x, const float* __restrict__ gamma, const float* __restrict__ beta,
    const float* __restrict__ stats, u16* __restrict__ hT,
    const u16* __restrict__ wproj_bf, const u16* __restrict__ wv_t, u16* __restrict__ wmega) {
    __shared__ u16 smem[2 * 128 * 64];
    int tid = threadIdx.x;
    if (blockIdx.z == 16) {  // Wpv = wproj_bf . wv_t^T -> wmega rows 1024..1535
        if (blockIdx.x >= 4 || blockIdx.y >= 4) return;
        int m0 = blockIdx.y << 7, n0 = blockIdx.x << 7;
        ACC_INIT;
        gemm_core_sb(wproj_bf, wv_t, CDIM, CDIM, CDIM, m0, n0, smem, smem + 128 * 64, acc);
        EPILOG_IDX;
#pragma unroll
        for (int i = 0; i < 4; ++i)
#pragma unroll
            for (int j = 0; j < 4; ++j)
#pragma unroll
                for (int r = 0; r < 4; ++r) {
                    int R = m0 + wm + i * 16 + (quad << 2) + r;
                    int Cc = n0 + wn + j * 16 + lrow;
                    wmega[(size_t)(1024 + R) * CDIM + Cc] = f2bf(acc[i][j][r]);
                }
        return;
    }
    u16* t = smem;
    int b = blockIdx.z, c0 = blockIdx.y << 6, n0 = blockIdx.x << 6;
    const float* xb = x + ((size_t)b * CDIM + c0) * NSPAT + n0;
#pragma unroll
    for (int p = 0; p < 4; ++p) {
        int cl = p * 16 + (tid >> 4);
        int nl = (tid & 15) << 2;
        int c = c0 + cl;
        int bg = b * NGROUP + (c >> 6);
        float ga = gamma[c] * stats[bg * 2 + 1];
        float be = beta[c] - stats[bg * 2] * ga;
        float4 v = *(const float4*)(xb + (size_t)cl * NSPAT + nl);
        u16* dst = &t[cl * TSTR + nl];
        dst[0] = f2bf(v.x * ga + be);
        dst[1] = f2bf(v.y * ga + be);
        dst[2] = f2bf(v.z * ga + be);
        dst[3] = f2bf(v.w * ga + be);
    }
    __syncthreads();
    u16* hb = hT + ((size_t)b * NSPAT + n0) * CDIM + c0;
#pragma unroll
    for (int p = 0; p < 4; ++p) {
        int nl = p * 16 + (tid >> 4);
        int cl4 = (tid & 15) << 2;
        ushort4 o;
        o.x = t[(cl4 + 0) * TSTR + nl];
        o.y = t[(cl4 + 1) * TSTR + nl];
        o.z = t[(cl4 + 2) * TSTR + nl];
        o.w = t[(cl4 + 3) * TSTR + nl];
        *(ushort4*)(hb + (size_t)nl * CDIM + cl4) = o;
    }
}

// ================= D3: qkv-mega: [q;k;WV] = wmega . h + [b_qkv(qk); bpv] =================
// grid (BATCH, 8, 6), 512 thr: y = n-tile(128), z = m-tile(256); z<4 -> q,k; z>=4 -> WV.
__global__ __launch_bounds__(512, 2) void qkv_kernel(
    const u16* __restrict__ wmega, const u16* __restrict__ hT,
    const float* __restrict__ b_qkv, const float* __restrict__ bpv,
    u16* __restrict__ qkT, u16* __restrict__ WV) {
    extern __shared__ u16 smem[];
    int z = blockIdx.x;
    int n0 = blockIdx.y << 7;
    int m0 = blockIdx.z << 8;
    const u16* Bb = hT + (size_t)z * CDIM * NSPAT;
    ACC_INIT8;
    gemm256(wmega, Bb, CDIM, CDIM, CDIM, m0, n0, smem, acc);
    EPILOG_IDX8;
    if (blockIdx.z < 4) {  // q,k rows: transposed packed store to qkT[n][o], ldc=1024
        u16* qk = qkT + (size_t)z * NSPAT * NSPAT;
#pragma unroll
        for (int mf = 0; mf < 8; ++mf)
#pragma unroll
            for (int nf = 0; nf < 2; ++nf) {
                int R0 = m0 + wrow * 128 + mf * 16 + (quad << 2);
                int Cc = n0 + wcol * 32 + nf * 16 + lrow;
                uint2 u;
                u.x = f2bf2(acc[mf][nf][0] + b_qkv[R0 + 0], acc[mf][nf][1] + b_qkv[R0 + 1]);
                u.y = f2bf2(acc[mf][nf][2] + b_qkv[R0 + 2], acc[mf][nf][3] + b_qkv[R0 + 3]);
                *(uint2*)&qk[(size_t)Cc * NSPAT + R0] = u;
            }
    } else {  // WV rows: natural store WV[o][n] + bpv
        u16* Wp = WV + (size_t)z * CDIM * NSPAT;
#pragma unroll
        for (int mf = 0; mf < 8; ++mf)
#pragma unroll
            for (int nf = 0; nf < 2; ++nf)
#pragma unroll
                for (int r = 0; r < 4; ++r) {
                    int R = m0 - 1024 + wrow * 128 + mf * 16 + (quad << 2) + r;
                    int Cc = n0 + wcol * 32 + nf * 16 + lrow;
                    Wp[(size_t)R * NSPAT + Cc] = f2bf(acc[mf][nf][r] + bpv[R]);
                }
    }
}

// ================= D4: scores (swapped operands): D[j][i] = k_j . q_i =================
// grid (BATCH, 8, 4), 512 thr: y = i-tile(128), z = j-tile(256).
__global__ __launch_bounds__(512, 2) void scores_kernel(
    const u16* __restrict__ qkT, u16* __restrict__ P, float* __restrict__ lsums, float scale) {
    extern __shared__ u16 smem[];
    int z = blockIdx.x;
    int n0 = blockIdx.y << 7;                // i tile (N-dim)
    int m0 = blockIdx.z << 8;                // j tile (M-dim)
    const u16* qb = qkT + (size_t)z * NSPAT * NSPAT;
    ACC_INIT8;
    gemm256(qb + CDIM, qb, CDIM, NSPAT, NSPAT, m0, n0, smem, acc);
    EPILOG_IDX8;
    u16* Pp = P + (size_t)z * NSPAT * NSPAT;
    float* ls = lsums + (size_t)z * NSPAT;
#pragma unroll
    for (int nf = 0; nf < 2; ++nf) {
        int Ci = n0 + wcol * 32 + nf * 16 + lrow;    // i (column of D)
        float part = 0.f;
#pragma unroll
        for (int mf = 0; mf < 8; ++mf) {
            int Rj0 = m0 + wrow * 128 + mf * 16 + (quad << 2);   // j rows, 4 consecutive
            float e0 = __expf(acc[mf][nf][0] * scale);
            float e1 = __expf(acc[mf][nf][1] * scale);
            float e2 = __expf(acc[mf][nf][2] * scale);
            float e3 = __expf(acc[mf][nf][3] * scale);
            part += (e0 + e1) + (e2 + e3);
            uint2 u;
            u.x = f2bf2(e0, e1);
            u.y = f2bf2(e2, e3);
            *(uint2*)&Pp[(size_t)Ci * NSPAT + Rj0] = u;
        }
        part += __shfl_xor(part, 16);
        part += __shfl_xor(part, 32);
        if (lane < 16) atomicAdd(&ls[Ci], part);
    }
}

// ================= D5: final (swapped operands): D[i][o] = P_i . WV_o =================
// grid (BATCH, 4, 4), 512 thr: y = o-tile(128), z = i-tile(256).
__global__ __launch_bounds__(512, 2) void final_kernel(
    const u16* __restrict__ WV, const u16* __restrict__ P, const float* __restrict__ lsums,
    const float* __restrict__ bias, const float* __restrict__ x, float* __restrict__ out) {
    extern __shared__ u16 smem[];
    int z = blockIdx.x;
    int n0 = blockIdx.y << 7;                // o tile (N-dim, 4 tiles)
    int m0 = blockIdx.z << 8;                // i tile (M-dim, 4 tiles)
    const u16* Pb = P + (size_t)z * NSPAT * NSPAT;
    const u16* WVb = WV + (size_t)z * CDIM * NSPAT;
    ACC_INIT8;
    gemm256(Pb, WVb, NSPAT, NSPAT, NSPAT, m0, n0, smem, acc);
    EPILOG_IDX8;
    float* Op = out + (size_t)z * CDIM * NSPAT;
    const float* xr = x + (size_t)z * CDIM * NSPAT;
    const float* li = lsums + (size_t)z * NSPAT;
#pragma unroll
    for (int mf = 0; mf < 8; ++mf) {
        int Ri0 = m0 + wrow * 128 + mf * 16 + (quad << 2);       // i, 4 consecutive
        float4 lv = *(const float4*)&li[Ri0];
        float s0 = __builtin_amdgcn_rcpf(lv.x);
        float s1 = __builtin_amdgcn_rcpf(lv.y);
        float s2 = __builtin_amdgcn_rcpf(lv.z);
        float s3 = __builtin_amdgcn_rcpf(lv.w);
#pragma unroll
        for (int nf = 0; nf < 2; ++nf) {
            int Co = n0 + wcol * 32 + nf * 16 + lrow;            // o
            float bv = bias[Co];
            size_t off = (size_t)Co * NSPAT + Ri0;
            float4 xv = *(const float4*)&xr[off];
            float4 o;
            o.x = acc[mf][nf][0] * s0 + bv + xv.x;
            o.y = acc[mf][nf][1] * s1 + bv + xv.y;
            o.z = acc[mf][nf][2] * s2 + bv + xv.z;
            o.w = acc[mf][nf][3] * s3 + bv + xv.w;
            *(float4*)&Op[off] = o;
        }
    }
}

// ================= launch =================
extern "C" void kernel_launch(void* const* d_in, const int* in_sizes, int n_in,
                              void* d_out, int out_size, void* d_ws, size_t ws_size,
                              hipStream_t stream) {
    const float* x      = (const float*)d_in[0];
    const float* gamma  = (const float*)d_in[1];
    const float* beta   = (const float*)d_in[2];
    const float* w_qkv  = (const float*)d_in[3];
    const float* b_qkv  = (const float*)d_in[4];
    const float* w_proj = (const float*)d_in[5];
    const float* b_proj = (const float*)d_in[6];
    float* out = (float*)d_out;

    const size_t CN = (size_t)CDIM * NSPAT;   // 524288
    const size_t NN = (size_t)NSPAT * NSPAT;  // 1048576
    const float SCALE = 0.044194173824159216f;
    const int LDS_BYTES = 2 * (TSA + TSB) * 2;   // 98304

    char* ws = (char*)d_ws;
    float* stats   = (float*)ws;                              // 1 KB
    float* bpv     = (float*)(ws + 1024);                     // 2 KB
    u16* wmega     = (u16*)(ws + 4096);                       // [Wq;Wk;Wpv] 1536x512 bf16
    u16* wproj_bf  = wmega + (size_t)3 * CDIM * CDIM;         // 0.5 MB
    u16* wv_t      = wproj_bf + (size_t)CDIM * CDIM;          // 0.5 MB
    u16* hT        = wv_t + (size_t)CDIM * CDIM;              // 16.8 MB [n][c]
    u16* qkT       = hT + BATCH * CN;                         // 33.5 MB [n][q,k:1024]
    u16* WV        = qkT + BATCH * NN;                        // 16.8 MB [o][n]
    u16* P         = WV + BATCH * CN;                         // 33.5 MB [i][j] unnorm
    float* lsums   = (float*)(P + BATCH * NN);                // 64 KB

    prep_kernel<<<984, 256, 0, stream>>>(
        w_qkv, w_proj, b_qkv, x, wmega, wproj_bf, wv_t, stats, lsums, bpv);

    gn_wpv_kernel<<<dim3(16, 8, 17), 256, 0, stream>>>(
        x, gamma, beta, stats, hT, wproj_bf, wv_t, wmega);

    qkv_kernel<<<dim3(BATCH, 8, 6), 512, LDS_BYTES, stream>>>(
        wmega, hT, b_qkv, bpv, qkT, WV);

    scores_kernel<<<dim3(BATCH, 8, 4), 512, LDS_BYTES, stream>>>(qkT, P, lsums, SCALE);

    final_kernel<<<dim3(BATCH, 4, 4), 512, LDS_BYTES, stream>>>(WV, P, lsums, b_proj, x, out);
}

// Round 5
// 138.706 us; speedup vs baseline: 1.4038x; 1.0807x over previous
//
#include <hip/hip_runtime.h>
#include <hip/hip_bf16.h>

typedef unsigned short u16;
typedef unsigned int u32;
typedef __attribute__((ext_vector_type(8))) short short8;
typedef __attribute__((ext_vector_type(4))) float floatx4;

#define BATCH 16
#define CDIM 512
#define NSPAT 1024
#define NGROUP 8

__device__ __forceinline__ u16 f2bf(float f) {
    unsigned u = __float_as_uint(f);
    u += 0x7FFFu + ((u >> 16) & 1u);   // RNE
    return (u16)(u >> 16);
}
__device__ __forceinline__ u32 f2bf2(float lo, float hi) {   // packed v_cvt_pk_bf16_f32
    __hip_bfloat162 h = __float22bfloat162_rn(make_float2(lo, hi));
    return *(u32*)&h;
}

__device__ __forceinline__ void load_lds16(const void* g, void* l) {
    __builtin_amdgcn_global_load_lds(
        (const __attribute__((address_space(1))) unsigned int*)g,
        (__attribute__((address_space(3))) unsigned int*)l, 16, 0, 0);
}

#define SBAR0 __builtin_amdgcn_sched_barrier(0)
#define BARRIER { SBAR0; __builtin_amdgcn_s_barrier(); SBAR0; }

// ================= D1 prep =================
__global__ __launch_bounds__(256) void prep_kernel(
    const float* __restrict__ w_qkv, const float* __restrict__ w_proj,
    const float* __restrict__ b_qkv, const float* __restrict__ x,
    u16* __restrict__ wmega, u16* __restrict__ wproj_bf, u16* __restrict__ wv_t,
    float* __restrict__ stats, float* __restrict__ lsums, float* __restrict__ bpv) {
    int b = blockIdx.x;
    int tid = threadIdx.x;
    if (b < 768) {
        const float* src = (b < 512) ? w_qkv : w_proj;
        u16* dst = (b < 512) ? wmega : wproj_bf;
        int i = (b < 512 ? b : b - 512) * 256 + tid;
        float4 v = ((const float4*)src)[i];
        u32* d = (u32*)dst;
        d[i * 2] = f2bf2(v.x, v.y);
        d[i * 2 + 1] = f2bf2(v.z, v.w);
        return;
    }
    if (b < 832) {  // transpose w_v (rows 1024..1535 of w_qkv) -> wv_t[ci][m], 64x64 tiles
        __shared__ u16 t[64 * 66];
        int bt = b - 768;
        int tx = bt & 7, ty = bt >> 3;
        const float* src = w_qkv + (size_t)(1024 + ty * 64) * CDIM + tx * 64;
#pragma unroll
        for (int p = 0; p < 4; ++p) {
            int r = p * 16 + (tid >> 4);
            int c4 = (tid & 15) << 2;
            float4 v = *(const float4*)(src + (size_t)r * CDIM + c4);
            u16* d = &t[r * 66 + c4];
            d[0] = f2bf(v.x); d[1] = f2bf(v.y); d[2] = f2bf(v.z); d[3] = f2bf(v.w);
        }
        __syncthreads();
        u16* dst = wv_t + (size_t)(tx * 64) * CDIM + ty * 64;
#pragma unroll
        for (int p = 0; p < 4; ++p) {
            int c = p * 16 + (tid >> 4);
            int r4 = (tid & 15) << 2;
            ushort4 o;
            o.x = t[(r4 + 0) * 66 + c];
            o.y = t[(r4 + 1) * 66 + c];
            o.z = t[(r4 + 2) * 66 + c];
            o.w = t[(r4 + 3) * 66 + c];
            *(ushort4*)(dst + (size_t)c * CDIM + r4) = o;
        }
        return;
    }
    if (b < 960) {  // stats
        __shared__ float rs[4], rss[4];
        int bg = b - 832;
        const float4* xv = (const float4*)(x + (size_t)bg * 65536);
        float s = 0.f, ss = 0.f;
        for (int i = tid; i < 16384; i += 256) {
            float4 v = xv[i];
            s += v.x + v.y + v.z + v.w;
            ss += v.x * v.x + v.y * v.y + v.z * v.z + v.w * v.w;
        }
#pragma unroll
        for (int off = 32; off; off >>= 1) { s += __shfl_down(s, off); ss += __shfl_down(ss, off); }
        int wave = tid >> 6, lane = tid & 63;
        if (lane == 0) { rs[wave] = s; rss[wave] = ss; }
        __syncthreads();
        if (tid == 0) {
            float S1 = rs[0] + rs[1] + rs[2] + rs[3];
            float S2 = rss[0] + rss[1] + rss[2] + rss[3];
            float mean = S1 * (1.f / 65536.f);
            float var = S2 * (1.f / 65536.f) - mean * mean;
            stats[bg * 2] = mean;
            stats[bg * 2 + 1] = rsqrtf(var + 1e-5f);
        }
        return;
    }
    if (b < 976) {  // zero lsums
        ((float4*)lsums)[(b - 960) * 256 + tid] = (float4){0.f, 0.f, 0.f, 0.f};
        return;
    }
    {   // bpv
        int o0 = (b - 976) * 64;
        int wave = tid >> 6, lane = tid & 63;
        const float4* bvv = (const float4*)(b_qkv + 1024);
        float4 v0 = bvv[lane * 2], v1 = bvv[lane * 2 + 1];
        for (int it = 0; it < 16; ++it) {
            int o = o0 + wave * 16 + it;
            const float4* wr = (const float4*)(w_proj + (size_t)o * CDIM);
            float4 a0 = wr[lane * 2], a1 = wr[lane * 2 + 1];
            float s = a0.x * v0.x + a0.y * v0.y + a0.z * v0.z + a0.w * v0.w
                    + a1.x * v1.x + a1.y * v1.y + a1.z * v1.z + a1.w * v1.w;
#pragma unroll
            for (int off = 32; off; off >>= 1) s += __shfl_down(s, off);
            if (lane == 0) bpv[o] = s;
        }
    }
}

// ================= legacy single-buffer 128x128x64 core (Wpv only, 256 thr) =================
__device__ __forceinline__ void stage_tile(
    const u16* __restrict__ Ab, const u16* __restrict__ Bb, int lda, int ldb,
    int m0, int n0, int k0, u16* As, u16* Bs) {
    int tid = threadIdx.x;
#pragma unroll
    for (int it = 0; it < 4; ++it) {
        int c = it * 256 + tid;
        int r = c >> 3, p = c & 7;
        int kc = p ^ (r & 7);
        load_lds16(Ab + (size_t)(m0 + r) * lda + k0 + (kc << 3), &As[c << 3]);
        load_lds16(Bb + (size_t)(n0 + r) * ldb + k0 + (kc << 3), &Bs[c << 3]);
    }
}

__device__ __forceinline__ void compute_tile(
    const u16* As, const u16* Bs, int wm, int wn, int quad, int lrow,
    floatx4 (&acc)[4][4]) {
#pragma unroll
    for (int s = 0; s < 2; ++s) {
        short8 af[4], bf[4];
#pragma unroll
        for (int i = 0; i < 4; ++i) {
            int R = wm + i * 16 + lrow;
            int p = (s * 4 + quad) ^ (R & 7);
            af[i] = *(const short8*)&As[(R << 6) + (p << 3)];
        }
#pragma unroll
        for (int j = 0; j < 4; ++j) {
            int R = wn + j * 16 + lrow;
            int p = (s * 4 + quad) ^ (R & 7);
            bf[j] = *(const short8*)&Bs[(R << 6) + (p << 3)];
        }
#pragma unroll
        for (int i = 0; i < 4; ++i)
#pragma unroll
            for (int j = 0; j < 4; ++j)
                acc[i][j] = __builtin_amdgcn_mfma_f32_16x16x32_bf16(af[i], bf[j], acc[i][j], 0, 0, 0);
    }
}

__device__ __forceinline__ void gemm_core_sb(
    const u16* __restrict__ Ab, const u16* __restrict__ Bb, int K, int lda, int ldb,
    int m0, int n0, u16* As, u16* Bs, floatx4 (&acc)[4][4]) {
    int tid = threadIdx.x;
    int lane = tid & 63, wave = tid >> 6, quad = lane >> 4, lrow = lane & 15;
    int wm = (wave >> 1) << 6, wn = (wave & 1) << 6;
    for (int k0 = 0; k0 < K; k0 += 64) {
        stage_tile(Ab, Bb, lda, ldb, m0, n0, k0, As, Bs);
        __syncthreads();
        compute_tile(As, Bs, wm, wn, quad, lrow, acc);
        __syncthreads();
    }
}

#define ACC_INIT floatx4 acc[4][4]; \
    _Pragma("unroll") for (int i = 0; i < 4; ++i) \
    _Pragma("unroll") for (int j = 0; j < 4; ++j) acc[i][j] = (floatx4){0.f, 0.f, 0.f, 0.f};

#define EPILOG_IDX int lane = threadIdx.x & 63, wave = threadIdx.x >> 6; \
    int quad = lane >> 4, lrow = lane & 15; \
    int wm = (wave >> 1) << 6, wn = (wave & 1) << 6;

// =====================================================================================
// 256x256x64 8-wave core (512 thr), m201 geometry: per-wave 128x64, acc[8][4].
// LDS 128KB: A 2 slots x 2 halves x (128 rho x 64 u16) @ [0,32768) u16
//            B 2 slots x 2 halves x (128 rho x 64 u16) @ [32768,65536) u16
// A-half qm: tile rows {wrow*128 + qm*64 + r}, rho = wrow*64 + r.
// B-half qn: tile cols {wcol*64 + qn*32 + r}, rho = wcol*32 + r.
// Row layout: 8 chunks of 8 u16; slot p holds global chunk p ^ (rho&7)  (XOR swizzle).
// 4 phases/K-tile: (qm,qn) = (0,0),(0,1),(1,0),(1,1); 16 MFMA each; af reused across qn.
// Staging 2 loads/thread/phase in need-order Ah0,Bh0,Bh1,Ah1 -> constant vmcnt(4).
// =====================================================================================
__device__ __forceinline__ void issueA2(
    const u16* __restrict__ Ab, int lda, int m0, int t, int h, u16* smem) {
    int tid = threadIdx.x;
    u16* base = smem + (t & 1) * 16384 + h * 8192;
#pragma unroll
    for (int l = 0; l < 2; ++l) {
        int c = l * 512 + tid;
        int rho = c >> 3, p = c & 7;
        int kc = p ^ (rho & 7);
        int r = ((rho >> 6) << 7) | (h << 6) | (rho & 63);
        load_lds16(Ab + (size_t)(m0 + r) * lda + (t << 6) + (kc << 3), base + (c << 3));
    }
}
__device__ __forceinline__ void issueB2(
    const u16* __restrict__ Bb, int ldb, int n0, int t, int h, u16* smem) {
    int tid = threadIdx.x;
    u16* base = smem + 32768 + (t & 1) * 16384 + h * 8192;
#pragma unroll
    for (int l = 0; l < 2; ++l) {
        int c = l * 512 + tid;
        int rho = c >> 3, p = c & 7;
        int kc = p ^ (rho & 7);
        int r = ((rho >> 5) << 6) | (h << 5) | (rho & 31);
        load_lds16(Bb + (size_t)(n0 + r) * ldb + (t << 6) + (kc << 3), base + (c << 3));
    }
}

template <bool RD_AF, int QM, int QN>
__device__ __forceinline__ void comp2(
    const u16* smem, int slot, int wrow, int wcol, int quad, int lrow,
    short8 (&af)[8], floatx4 (&acc)[8][4]) {
    const u16* Ah = smem + slot * 16384 + QM * 8192;
    const u16* Bh = smem + 32768 + slot * 16384 + QN * 8192;
    short8 bf[4];
#pragma unroll
    for (int ks = 0; ks < 2; ++ks) {
        if (RD_AF) {
#pragma unroll
            for (int i = 0; i < 4; ++i) {
                int rho = wrow * 64 + i * 16 + lrow;
                int p = (ks * 4 + quad) ^ (lrow & 7);
                af[ks * 4 + i] = *(const short8*)&Ah[(rho << 6) + (p << 3)];
            }
        }
#pragma unroll
        for (int j = 0; j < 2; ++j) {
            int rho = wcol * 32 + j * 16 + lrow;
            int p = (ks * 4 + quad) ^ (lrow & 7);
            bf[ks * 2 + j] = *(const short8*)&Bh[(rho << 6) + (p << 3)];
        }
    }
    asm volatile("s_waitcnt lgkmcnt(0)" ::: "memory");
    SBAR0;
    __builtin_amdgcn_s_setprio(1);
#pragma unroll
    for (int ks = 0; ks < 2; ++ks)
#pragma unroll
        for (int i = 0; i < 4; ++i)
#pragma unroll
            for (int j = 0; j < 2; ++j)
                acc[QM * 4 + i][QN * 2 + j] = __builtin_amdgcn_mfma_f32_16x16x32_bf16(
                    af[ks * 4 + i], bf[ks * 2 + j], acc[QM * 4 + i][QN * 2 + j], 0, 0, 0);
    __builtin_amdgcn_s_setprio(0);
}

__device__ __forceinline__ void gemm256x256(
    const u16* __restrict__ Ab, const u16* __restrict__ Bb, int K, int lda, int ldb,
    int m0, int n0, u16* smem, floatx4 (&acc)[8][4]) {
    int tid = threadIdx.x;
    int lane = tid & 63, wave = tid >> 6;
    int quad = lane >> 4, lrow = lane & 15;
    int wrow = wave >> 2, wcol = wave & 3;
    int nt = K >> 6;
    short8 af[8];
    // prologue: tile0 halves in need-order (FIFO: Ah0,Bh0,Bh1,Ah1 = 8 loads/thread)
    issueA2(Ab, lda, m0, 0, 0, smem);
    issueB2(Bb, ldb, n0, 0, 0, smem);
    issueB2(Bb, ldb, n0, 0, 1, smem);
    issueA2(Ab, lda, m0, 0, 1, smem);
    for (int t = 0; t < nt; ++t) {
        int slot = t & 1;
        bool nxt = (t + 1 < nt);
        // ---- P1 (qm0,qn0): needs Ah0(t),Bh0(t)
        asm volatile("s_waitcnt vmcnt(4)" ::: "memory");
        BARRIER;
        if (nxt) issueA2(Ab, lda, m0, t + 1, 0, smem);
        comp2<true, 0, 0>(smem, slot, wrow, wcol, quad, lrow, af, acc);
        BARRIER;
        // ---- P2 (qm0,qn1): needs Bh1(t)
        if (nxt) { asm volatile("s_waitcnt vmcnt(4)" ::: "memory"); }
        else     { asm volatile("s_waitcnt vmcnt(2)" ::: "memory"); }
        BARRIER;
        if (nxt) issueB2(Bb, ldb, n0, t + 1, 0, smem);
        comp2<false, 0, 1>(smem, slot, wrow, wcol, quad, lrow, af, acc);
        BARRIER;
        // ---- P3 (qm1,qn0): needs Ah1(t)
        if (nxt) { asm volatile("s_waitcnt vmcnt(4)" ::: "memory"); }
        else     { asm volatile("s_waitcnt vmcnt(0)" ::: "memory"); }
        BARRIER;
        if (nxt) issueB2(Bb, ldb, n0, t + 1, 1, smem);
        comp2<true, 1, 0>(smem, slot, wrow, wcol, quad, lrow, af, acc);
        BARRIER;
        // ---- P4 (qm1,qn1): no new data (entry barrier elided)
        if (nxt) issueA2(Ab, lda, m0, t + 1, 1, smem);
        comp2<false, 1, 1>(smem, slot, wrow, wcol, quad, lrow, af, acc);
        BARRIER;
    }
}

// =====================================================================================
// 256x128x64 8-wave core (512 thr): per-wave 64x64, acc[4][4], 2 phases/K-tile.
// LDS 96KB: A 2 slots x (256 x 64 u16 linear) @ [0,32768) u16
//           B 2 slots x 2 halves x (64 rho x 64 u16) @ [32768,49152) u16
// B-half qn: tile cols {wcol*64 + qn*32 + r}, rho = wcol*32 + r.
// Staging order per tile: Bh0[1], A[4], Bh1[1] -> waits vmcnt(1) / vmcnt(5).
// =====================================================================================
__device__ __forceinline__ void issueA4(
    const u16* __restrict__ Ab, int lda, int m0, int t, u16* smem) {
    int tid = threadIdx.x;
    u16* base = smem + (t & 1) * 16384;
#pragma unroll
    for (int l = 0; l < 4; ++l) {
        int c = l * 512 + tid;
        int rho = c >> 3, p = c & 7;
        int kc = p ^ (rho & 7);
        load_lds16(Ab + (size_t)(m0 + rho) * lda + (t << 6) + (kc << 3), base + (c << 3));
    }
}
__device__ __forceinline__ void issueB4(
    const u16* __restrict__ Bb, int ldb, int n0, int t, int h, u16* smem) {
    int tid = threadIdx.x;
    u16* base = smem + 32768 + (t & 1) * 8192 + h * 4096;
    int rho = tid >> 3, p = tid & 7;
    int kc = p ^ (rho & 7);
    int r = ((rho >> 5) << 6) | (h << 5) | (rho & 31);
    load_lds16(Bb + (size_t)(n0 + r) * ldb + (t << 6) + (kc << 3), base + (tid << 3));
}

template <bool RD_AF, int QN>
__device__ __forceinline__ void comp4(
    const u16* smem, int slot, int wrow, int wcol, int quad, int lrow,
    short8 (&af)[8], floatx4 (&acc)[4][4]) {
    const u16* Ah = smem + slot * 16384;
    const u16* Bh = smem + 32768 + slot * 8192 + QN * 4096;
    short8 bf[4];
#pragma unroll
    for (int ks = 0; ks < 2; ++ks) {
        if (RD_AF) {
#pragma unroll
            for (int i = 0; i < 4; ++i) {
                int rho = wrow * 64 + i * 16 + lrow;
                int p = (ks * 4 + quad) ^ (lrow & 7);
                af[ks * 4 + i] = *(const short8*)&Ah[(rho << 6) + (p << 3)];
            }
        }
#pragma unroll
        for (int j = 0; j < 2; ++j) {
            int rho = wcol * 32 + j * 16 + lrow;
            int p = (ks * 4 + quad) ^ (lrow & 7);
            bf[ks * 2 + j] = *(const short8*)&Bh[(rho << 6) + (p << 3)];
        }
    }
    asm volatile("s_waitcnt lgkmcnt(0)" ::: "memory");
    SBAR0;
    __builtin_amdgcn_s_setprio(1);
#pragma unroll
    for (int ks = 0; ks < 2; ++ks)
#pragma unroll
        for (int i = 0; i < 4; ++i)
#pragma unroll
            for (int j = 0; j < 2; ++j)
                acc[i][QN * 2 + j] = __builtin_amdgcn_mfma_f32_16x16x32_bf16(
                    af[ks * 4 + i], bf[ks * 2 + j], acc[i][QN * 2 + j], 0, 0, 0);
    __builtin_amdgcn_s_setprio(0);
}

__device__ __forceinline__ void gemm256x128(
    const u16* __restrict__ Ab, const u16* __restrict__ Bb, int K, int lda, int ldb,
    int m0, int n0, u16* smem, floatx4 (&acc)[4][4]) {
    int tid = threadIdx.x;
    int lane = tid & 63, wave = tid >> 6;
    int quad = lane >> 4, lrow = lane & 15;
    int wrow = wave >> 1, wcol = wave & 1;
    int nt = K >> 6;
    short8 af[8];
    // prologue (FIFO: Bh0[1], A[4], Bh1[1])
    issueB4(Bb, ldb, n0, 0, 0, smem);
    issueA4(Ab, lda, m0, 0, smem);
    issueB4(Bb, ldb, n0, 0, 1, smem);
    for (int t = 0; t < nt; ++t) {
        int slot = t & 1;
        bool nxt = (t + 1 < nt);
        // ---- P1 (qn0): needs Bh0(t) + A(t)
        asm volatile("s_waitcnt vmcnt(1)" ::: "memory");
        BARRIER;
        if (nxt) { issueB4(Bb, ldb, n0, t + 1, 0, smem); issueA4(Ab, lda, m0, t + 1, smem); }
        comp4<true, 0>(smem, slot, wrow, wcol, quad, lrow, af, acc);
        BARRIER;
        // ---- P2 (qn1): needs Bh1(t)
        if (nxt) { asm volatile("s_waitcnt vmcnt(5)" ::: "memory"); }
        else     { asm volatile("s_waitcnt vmcnt(0)" ::: "memory"); }
        BARRIER;
        if (nxt) issueB4(Bb, ldb, n0, t + 1, 1, smem);
        comp4<false, 1>(smem, slot, wrow, wcol, quad, lrow, af, acc);
        BARRIER;
    }
}

#define ACC_INIT84 floatx4 acc[8][4]; \
    _Pragma("unroll") for (int i = 0; i < 8; ++i) \
    _Pragma("unroll") for (int j = 0; j < 4; ++j) acc[i][j] = (floatx4){0.f, 0.f, 0.f, 0.f};

#define ACC_INIT44 floatx4 acc[4][4]; \
    _Pragma("unroll") for (int i = 0; i < 4; ++i) \
    _Pragma("unroll") for (int j = 0; j < 4; ++j) acc[i][j] = (floatx4){0.f, 0.f, 0.f, 0.f};

// ================= D2: GN apply+transpose (z<16) + Wpv GEMM (z==16) =================
#define TSTR 66
__global__ __launch_bounds__(256) void gn_wpv_kernel(
    const float* __restrict__ x, const float* __restrict__ gamma, const float* __restrict__ beta,
    const float* __restrict__ stats, u16* __restrict__ hT,
    const u16* __restrict__ wproj_bf, const u16* __restrict__ wv_t, u16* __restrict__ wmega) {
    __shared__ u16 smem[2 * 128 * 64];
    int tid = threadIdx.x;
    if (blockIdx.z == 16) {  // Wpv = wproj_bf . wv_t^T -> wmega rows 1024..1535
        if (blockIdx.x >= 4 || blockIdx.y >= 4) return;
        int m0 = blockIdx.y << 7, n0 = blockIdx.x << 7;
        ACC_INIT;
        gemm_core_sb(wproj_bf, wv_t, CDIM, CDIM, CDIM, m0, n0, smem, smem + 128 * 64, acc);
        EPILOG_IDX;
#pragma unroll
        for (int i = 0; i < 4; ++i)
#pragma unroll
            for (int j = 0; j < 4; ++j)
#pragma unroll
                for (int r = 0; r < 4; ++r) {
                    int R = m0 + wm + i * 16 + (quad << 2) + r;
                    int Cc = n0 + wn + j * 16 + lrow;
                    wmega[(size_t)(1024 + R) * CDIM + Cc] = f2bf(acc[i][j][r]);
                }
        return;
    }
    u16* t = smem;
    int b = blockIdx.z, c0 = blockIdx.y << 6, n0 = blockIdx.x << 6;
    const float* xb = x + ((size_t)b * CDIM + c0) * NSPAT + n0;
#pragma unroll
    for (int p = 0; p < 4; ++p) {
        int cl = p * 16 + (tid >> 4);
        int nl = (tid & 15) << 2;
        int c = c0 + cl;
        int bg = b * NGROUP + (c >> 6);
        float ga = gamma[c] * stats[bg * 2 + 1];
        float be = beta[c] - stats[bg * 2] * ga;
        float4 v = *(const float4*)(xb + (size_t)cl * NSPAT + nl);
        u16* dst = &t[cl * TSTR + nl];
        dst[0] = f2bf(v.x * ga + be);
        dst[1] = f2bf(v.y * ga + be);
        dst[2] = f2bf(v.z * ga + be);
        dst[3] = f2bf(v.w * ga + be);
    }
    __syncthreads();
    u16* hb = hT + ((size_t)b * NSPAT + n0) * CDIM + c0;
#pragma unroll
    for (int p = 0; p < 4; ++p) {
        int nl = p * 16 + (tid >> 4);
        int cl4 = (tid & 15) << 2;
        ushort4 o;
        o.x = t[(cl4 + 0) * TSTR + nl];
        o.y = t[(cl4 + 1) * TSTR + nl];
        o.z = t[(cl4 + 2) * TSTR + nl];
        o.w = t[(cl4 + 3) * TSTR + nl];
        *(ushort4*)(hb + (size_t)nl * CDIM + cl4) = o;
    }
}

// ================= D3: qkv-mega: [q;k;WV] = wmega . h + [b_qkv(qk); bpv] =================
// grid (BATCH, 4, 6), 512 thr: y = n-tile(256), z = m-tile(256); z<4 -> q,k; z>=4 -> WV.
__global__ __launch_bounds__(512, 2) void qkv_kernel(
    const u16* __restrict__ wmega, const u16* __restrict__ hT,
    const float* __restrict__ b_qkv, const float* __restrict__ bpv,
    u16* __restrict__ qkT, u16* __restrict__ WV) {
    extern __shared__ u16 smem[];
    int z = blockIdx.x;
    int n0 = blockIdx.y << 8;
    int m0 = blockIdx.z << 8;
    const u16* Bb = hT + (size_t)z * CDIM * NSPAT;
    ACC_INIT84;
    gemm256x256(wmega, Bb, CDIM, CDIM, CDIM, m0, n0, smem, acc);
    int lane = threadIdx.x & 63, wave = threadIdx.x >> 6;
    int quad = lane >> 4, lrow = lane & 15;
    int wrow = wave >> 2, wcol = wave & 3;
    if (blockIdx.z < 4) {  // q,k rows: transposed packed store to qkT[n][o], ldc=1024
        u16* qk = qkT + (size_t)z * NSPAT * NSPAT;
#pragma unroll
        for (int mf = 0; mf < 8; ++mf) {
            int R0 = m0 + wrow * 128 + mf * 16 + (quad << 2);
            float4 bv = *(const float4*)&b_qkv[R0];
#pragma unroll
            for (int nf = 0; nf < 4; ++nf) {
                int Cc = n0 + wcol * 64 + nf * 16 + lrow;
                uint2 u;
                u.x = f2bf2(acc[mf][nf][0] + bv.x, acc[mf][nf][1] + bv.y);
                u.y = f2bf2(acc[mf][nf][2] + bv.z, acc[mf][nf][3] + bv.w);
                *(uint2*)&qk[(size_t)Cc * NSPAT + R0] = u;
            }
        }
    } else {  // WV rows: natural store WV[o][n] + bpv
        u16* Wp = WV + (size_t)z * CDIM * NSPAT;
#pragma unroll
        for (int mf = 0; mf < 8; ++mf) {
            int R = m0 - 1024 + wrow * 128 + mf * 16 + (quad << 2);
            float4 pv = *(const float4*)&bpv[R];
#pragma unroll
            for (int nf = 0; nf < 4; ++nf) {
                int Cc = n0 + wcol * 64 + nf * 16 + lrow;
                Wp[(size_t)(R + 0) * NSPAT + Cc] = f2bf(acc[mf][nf][0] + pv.x);
                Wp[(size_t)(R + 1) * NSPAT + Cc] = f2bf(acc[mf][nf][1] + pv.y);
                Wp[(size_t)(R + 2) * NSPAT + Cc] = f2bf(acc[mf][nf][2] + pv.z);
                Wp[(size_t)(R + 3) * NSPAT + Cc] = f2bf(acc[mf][nf][3] + pv.w);
            }
        }
    }
}

// ================= D4: scores (swapped operands): D[j][i] = k_j . q_i =================
// grid (BATCH, 4, 4), 512 thr: y = i-tile(256), z = j-tile(256).
__global__ __launch_bounds__(512, 2) void scores_kernel(
    const u16* __restrict__ qkT, u16* __restrict__ P, float* __restrict__ lsums, float scale) {
    extern __shared__ u16 smem[];
    int z = blockIdx.x;
    int n0 = blockIdx.y << 8;                // i tile (N-dim)
    int m0 = blockIdx.z << 8;                // j tile (M-dim)
    const u16* qb = qkT + (size_t)z * NSPAT * NSPAT;
    ACC_INIT84;
    gemm256x256(qb + CDIM, qb, CDIM, NSPAT, NSPAT, m0, n0, smem, acc);
    int lane = threadIdx.x & 63, wave = threadIdx.x >> 6;
    int quad = lane >> 4, lrow = lane & 15;
    int wrow = wave >> 2, wcol = wave & 3;
    u16* Pp = P + (size_t)z * NSPAT * NSPAT;
    float* ls = lsums + (size_t)z * NSPAT;
#pragma unroll
    for (int nf = 0; nf < 4; ++nf) {
        int Ci = n0 + wcol * 64 + nf * 16 + lrow;    // i (column of D)
        float part = 0.f;
#pragma unroll
        for (int mf = 0; mf < 8; ++mf) {
            int Rj0 = m0 + wrow * 128 + mf * 16 + (quad << 2);   // j rows, 4 consecutive
            float e0 = __expf(acc[mf][nf][0] * scale);
            float e1 = __expf(acc[mf][nf][1] * scale);
            float e2 = __expf(acc[mf][nf][2] * scale);
            float e3 = __expf(acc[mf][nf][3] * scale);
            part += (e0 + e1) + (e2 + e3);
            uint2 u;
            u.x = f2bf2(e0, e1);
            u.y = f2bf2(e2, e3);
            *(uint2*)&Pp[(size_t)Ci * NSPAT + Rj0] = u;
        }
        part += __shfl_xor(part, 16);
        part += __shfl_xor(part, 32);
        if (lane < 16) atomicAdd(&ls[Ci], part);
    }
}

// ================= D5: final (swapped operands): D[i][o] = P_i . WV_o =================
// grid (BATCH, 4, 4), 512 thr: y = o-tile(128), z = i-tile(256).
__global__ __launch_bounds__(512, 2) void final_kernel(
    const u16* __restrict__ WV, const u16* __restrict__ P, const float* __restrict__ lsums,
    const float* __restrict__ bias, const float* __restrict__ x, float* __restrict__ out) {
    extern __shared__ u16 smem[];
    int z = blockIdx.x;
    int n0 = blockIdx.y << 7;                // o tile (N-dim, 4 tiles of 128)
    int m0 = blockIdx.z << 8;                // i tile (M-dim, 4 tiles of 256)
    const u16* Pb = P + (size_t)z * NSPAT * NSPAT;
    const u16* WVb = WV + (size_t)z * CDIM * NSPAT;
    ACC_INIT44;
    gemm256x128(Pb, WVb, NSPAT, NSPAT, NSPAT, m0, n0, smem, acc);
    int lane = threadIdx.x & 63, wave = threadIdx.x >> 6;
    int quad = lane >> 4, lrow = lane & 15;
    int wrow = wave >> 1, wcol = wave & 1;
    float* Op = out + (size_t)z * CDIM * NSPAT;
    const float* xr = x + (size_t)z * CDIM * NSPAT;
    const float* li = lsums + (size_t)z * NSPAT;
#pragma unroll
    for (int mf = 0; mf < 4; ++mf) {
        int Ri0 = m0 + wrow * 64 + mf * 16 + (quad << 2);        // i, 4 consecutive
        float4 lv = *(const float4*)&li[Ri0];
        float s0 = __builtin_amdgcn_rcpf(lv.x);
        float s1 = __builtin_amdgcn_rcpf(lv.y);
        float s2 = __builtin_amdgcn_rcpf(lv.z);
        float s3 = __builtin_amdgcn_rcpf(lv.w);
#pragma unroll
        for (int nf = 0; nf < 4; ++nf) {
            int Co = n0 + wcol * 64 + nf * 16 + lrow;            // o
            float bv = bias[Co];
            size_t off = (size_t)Co * NSPAT + Ri0;
            float4 xv = *(const float4*)&xr[off];
            float4 o;
            o.x = acc[mf][nf][0] * s0 + bv + xv.x;
            o.y = acc[mf][nf][1] * s1 + bv + xv.y;
            o.z = acc[mf][nf][2] * s2 + bv + xv.z;
            o.w = acc[mf][nf][3] * s3 + bv + xv.w;
            *(float4*)&Op[off] = o;
        }
    }
}

// ================= launch =================
extern "C" void kernel_launch(void* const* d_in, const int* in_sizes, int n_in,
                              void* d_out, int out_size, void* d_ws, size_t ws_size,
                              hipStream_t stream) {
    const float* x      = (const float*)d_in[0];
    const float* gamma  = (const float*)d_in[1];
    const float* beta   = (const float*)d_in[2];
    const float* w_qkv  = (const float*)d_in[3];
    const float* b_qkv  = (const float*)d_in[4];
    const float* w_proj = (const float*)d_in[5];
    const float* b_proj = (const float*)d_in[6];
    float* out = (float*)d_out;

    const size_t CN = (size_t)CDIM * NSPAT;   // 524288
    const size_t NN = (size_t)NSPAT * NSPAT;  // 1048576
    const float SCALE = 0.044194173824159216f;
    const int LDS_BIG = 131072;   // 256x256 core: 2x(32KB A + 32KB B)
    const int LDS_MED = 98304;    // 256x128 core: 2x(32KB A + 16KB B)

    // One-time opt-in for >64KB dynamic LDS (graph-capture-safe: no alloc/sync).
    static bool lds_attr_done = false;
    if (!lds_attr_done) {
        hipFuncSetAttribute((const void*)qkv_kernel,
                            hipFuncAttributeMaxDynamicSharedMemorySize, LDS_BIG);
        hipFuncSetAttribute((const void*)scores_kernel,
                            hipFuncAttributeMaxDynamicSharedMemorySize, LDS_BIG);
        hipFuncSetAttribute((const void*)final_kernel,
                            hipFuncAttributeMaxDynamicSharedMemorySize, LDS_MED);
        lds_attr_done = true;
    }

    char* ws = (char*)d_ws;
    float* stats   = (float*)ws;                              // 1 KB
    float* bpv     = (float*)(ws + 1024);                     // 2 KB
    u16* wmega     = (u16*)(ws + 4096);                       // [Wq;Wk;Wpv] 1536x512 bf16
    u16* wproj_bf  = wmega + (size_t)3 * CDIM * CDIM;         // 0.5 MB
    u16* wv_t      = wproj_bf + (size_t)CDIM * CDIM;          // 0.5 MB
    u16* hT        = wv_t + (size_t)CDIM * CDIM;              // 16.8 MB [n][c]
    u16* qkT       = hT + BATCH * CN;                         // 33.5 MB [n][q,k:1024]
    u16* WV        = qkT + BATCH * NN;                        // 16.8 MB [o][n]
    u16* P         = WV + BATCH * CN;                         // 33.5 MB [i][j] unnorm
    float* lsums   = (float*)(P + BATCH * NN);                // 64 KB

    prep_kernel<<<984, 256, 0, stream>>>(
        w_qkv, w_proj, b_qkv, x, wmega, wproj_bf, wv_t, stats, lsums, bpv);

    gn_wpv_kernel<<<dim3(16, 8, 17), 256, 0, stream>>>(
        x, gamma, beta, stats, hT, wproj_bf, wv_t, wmega);

    qkv_kernel<<<dim3(BATCH, 4, 6), 512, LDS_BIG, stream>>>(
        wmega, hT, b_qkv, bpv, qkT, WV);

    scores_kernel<<<dim3(BATCH, 4, 4), 512, LDS_BIG, stream>>>(qkT, P, lsums, SCALE);

    final_kernel<<<dim3(BATCH, 4, 4), 512, LDS_MED, stream>>>(WV, P, lsums, b_proj, x, out);
}

// Round 6
// 134.780 us; speedup vs baseline: 1.4447x; 1.0291x over previous
//
#include <hip/hip_runtime.h>
#include <hip/hip_bf16.h>

typedef unsigned short u16;
typedef unsigned int u32;
typedef __attribute__((ext_vector_type(8))) short short8;
typedef __attribute__((ext_vector_type(4))) float floatx4;

#define BATCH 16
#define CDIM 512
#define NSPAT 1024
#define NGROUP 8

__device__ __forceinline__ u16 f2bf(float f) {
    unsigned u = __float_as_uint(f);
    u += 0x7FFFu + ((u >> 16) & 1u);   // RNE
    return (u16)(u >> 16);
}
__device__ __forceinline__ u32 f2bf2(float lo, float hi) {   // packed v_cvt_pk_bf16_f32
    __hip_bfloat162 h = __float22bfloat162_rn(make_float2(lo, hi));
    return *(u32*)&h;
}

__device__ __forceinline__ void load_lds16(const void* g, void* l) {
    __builtin_amdgcn_global_load_lds(
        (const __attribute__((address_space(1))) unsigned int*)g,
        (__attribute__((address_space(3))) unsigned int*)l, 16, 0, 0);
}

#define SBAR0 __builtin_amdgcn_sched_barrier(0)
#define BARRIER { SBAR0; __builtin_amdgcn_s_barrier(); SBAR0; }

// ================= D1 prep =================
__global__ __launch_bounds__(256) void prep_kernel(
    const float* __restrict__ w_qkv, const float* __restrict__ w_proj,
    const float* __restrict__ b_qkv, const float* __restrict__ x,
    u16* __restrict__ wmega, u16* __restrict__ wproj_bf, u16* __restrict__ wv_t,
    float* __restrict__ stats, float* __restrict__ lsums, float* __restrict__ bpv) {
    int b = blockIdx.x;
    int tid = threadIdx.x;
    if (b < 768) {
        const float* src = (b < 512) ? w_qkv : w_proj;
        u16* dst = (b < 512) ? wmega : wproj_bf;
        int i = (b < 512 ? b : b - 512) * 256 + tid;
        float4 v = ((const float4*)src)[i];
        u32* d = (u32*)dst;
        d[i * 2] = f2bf2(v.x, v.y);
        d[i * 2 + 1] = f2bf2(v.z, v.w);
        return;
    }
    if (b < 832) {  // transpose w_v (rows 1024..1535 of w_qkv) -> wv_t[ci][m], 64x64 tiles
        __shared__ u16 t[64 * 66];
        int bt = b - 768;
        int tx = bt & 7, ty = bt >> 3;
        const float* src = w_qkv + (size_t)(1024 + ty * 64) * CDIM + tx * 64;
#pragma unroll
        for (int p = 0; p < 4; ++p) {
            int r = p * 16 + (tid >> 4);
            int c4 = (tid & 15) << 2;
            float4 v = *(const float4*)(src + (size_t)r * CDIM + c4);
            u16* d = &t[r * 66 + c4];
            d[0] = f2bf(v.x); d[1] = f2bf(v.y); d[2] = f2bf(v.z); d[3] = f2bf(v.w);
        }
        __syncthreads();
        u16* dst = wv_t + (size_t)(tx * 64) * CDIM + ty * 64;
#pragma unroll
        for (int p = 0; p < 4; ++p) {
            int c = p * 16 + (tid >> 4);
            int r4 = (tid & 15) << 2;
            ushort4 o;
            o.x = t[(r4 + 0) * 66 + c];
            o.y = t[(r4 + 1) * 66 + c];
            o.z = t[(r4 + 2) * 66 + c];
            o.w = t[(r4 + 3) * 66 + c];
            *(ushort4*)(dst + (size_t)c * CDIM + r4) = o;
        }
        return;
    }
    if (b < 960) {  // stats
        __shared__ float rs[4], rss[4];
        int bg = b - 832;
        const float4* xv = (const float4*)(x + (size_t)bg * 65536);
        float s = 0.f, ss = 0.f;
        for (int i = tid; i < 16384; i += 256) {
            float4 v = xv[i];
            s += v.x + v.y + v.z + v.w;
            ss += v.x * v.x + v.y * v.y + v.z * v.z + v.w * v.w;
        }
#pragma unroll
        for (int off = 32; off; off >>= 1) { s += __shfl_down(s, off); ss += __shfl_down(ss, off); }
        int wave = tid >> 6, lane = tid & 63;
        if (lane == 0) { rs[wave] = s; rss[wave] = ss; }
        __syncthreads();
        if (tid == 0) {
            float S1 = rs[0] + rs[1] + rs[2] + rs[3];
            float S2 = rss[0] + rss[1] + rss[2] + rss[3];
            float mean = S1 * (1.f / 65536.f);
            float var = S2 * (1.f / 65536.f) - mean * mean;
            stats[bg * 2] = mean;
            stats[bg * 2 + 1] = rsqrtf(var + 1e-5f);
        }
        return;
    }
    if (b < 976) {  // zero lsums
        ((float4*)lsums)[(b - 960) * 256 + tid] = (float4){0.f, 0.f, 0.f, 0.f};
        return;
    }
    {   // bpv
        int o0 = (b - 976) * 64;
        int wave = tid >> 6, lane = tid & 63;
        const float4* bvv = (const float4*)(b_qkv + 1024);
        float4 v0 = bvv[lane * 2], v1 = bvv[lane * 2 + 1];
        for (int it = 0; it < 16; ++it) {
            int o = o0 + wave * 16 + it;
            const float4* wr = (const float4*)(w_proj + (size_t)o * CDIM);
            float4 a0 = wr[lane * 2], a1 = wr[lane * 2 + 1];
            float s = a0.x * v0.x + a0.y * v0.y + a0.z * v0.z + a0.w * v0.w
                    + a1.x * v1.x + a1.y * v1.y + a1.z * v1.z + a1.w * v1.w;
#pragma unroll
            for (int off = 32; off; off >>= 1) s += __shfl_down(s, off);
            if (lane == 0) bpv[o] = s;
        }
    }
}

// ================= legacy single-buffer 128x128x64 core (Wpv only, 256 thr) =================
__device__ __forceinline__ void stage_tile(
    const u16* __restrict__ Ab, const u16* __restrict__ Bb, int lda, int ldb,
    int m0, int n0, int k0, u16* As, u16* Bs) {
    int tid = threadIdx.x;
#pragma unroll
    for (int it = 0; it < 4; ++it) {
        int c = it * 256 + tid;
        int r = c >> 3, p = c & 7;
        int kc = p ^ (r & 7);
        load_lds16(Ab + (size_t)(m0 + r) * lda + k0 + (kc << 3), &As[c << 3]);
        load_lds16(Bb + (size_t)(n0 + r) * ldb + k0 + (kc << 3), &Bs[c << 3]);
    }
}

__device__ __forceinline__ void compute_tile(
    const u16* As, const u16* Bs, int wm, int wn, int quad, int lrow,
    floatx4 (&acc)[4][4]) {
#pragma unroll
    for (int s = 0; s < 2; ++s) {
        short8 af[4], bf[4];
#pragma unroll
        for (int i = 0; i < 4; ++i) {
            int R = wm + i * 16 + lrow;
            int p = (s * 4 + quad) ^ (R & 7);
            af[i] = *(const short8*)&As[(R << 6) + (p << 3)];
        }
#pragma unroll
        for (int j = 0; j < 4; ++j) {
            int R = wn + j * 16 + lrow;
            int p = (s * 4 + quad) ^ (R & 7);
            bf[j] = *(const short8*)&Bs[(R << 6) + (p << 3)];
        }
#pragma unroll
        for (int i = 0; i < 4; ++i)
#pragma unroll
            for (int j = 0; j < 4; ++j)
                acc[i][j] = __builtin_amdgcn_mfma_f32_16x16x32_bf16(af[i], bf[j], acc[i][j], 0, 0, 0);
    }
}

__device__ __forceinline__ void gemm_core_sb(
    const u16* __restrict__ Ab, const u16* __restrict__ Bb, int K, int lda, int ldb,
    int m0, int n0, u16* As, u16* Bs, floatx4 (&acc)[4][4]) {
    int tid = threadIdx.x;
    int lane = tid & 63, wave = tid >> 6, quad = lane >> 4, lrow = lane & 15;
    int wm = (wave >> 1) << 6, wn = (wave & 1) << 6;
    for (int k0 = 0; k0 < K; k0 += 64) {
        stage_tile(Ab, Bb, lda, ldb, m0, n0, k0, As, Bs);
        __syncthreads();
        compute_tile(As, Bs, wm, wn, quad, lrow, acc);
        __syncthreads();
    }
}

#define ACC_INIT floatx4 acc[4][4]; \
    _Pragma("unroll") for (int i = 0; i < 4; ++i) \
    _Pragma("unroll") for (int j = 0; j < 4; ++j) acc[i][j] = (floatx4){0.f, 0.f, 0.f, 0.f};

#define EPILOG_IDX int lane = threadIdx.x & 63, wave = threadIdx.x >> 6; \
    int quad = lane >> 4, lrow = lane & 15; \
    int wm = (wave >> 1) << 6, wn = (wave & 1) << 6;

// =====================================================================================
// 256x256x64 8-wave core (512 thr), per-wave 128x64, acc[8][4].
// LDS 128KB double-buffered (A: 2x16384 u16, B: 2x16384 u16), XOR-swizzled rows.
// Per K-tile: ONE staging burst (8 load instrs, next tile), counted vmcnt(8), TWO
// barriers, then one free-scheduled compute region: 24 ds_read_b128 (bf cached
// across qm halves) + 64 MFMA — compiler interleaves with fine-grained lgkmcnt.
// Hazard audit: reads(slot s) never conflict with staging(slot s~); staging t+1 over
// t-1's slot is fenced by B1 (t-1 reads are register-consumed before B1).
// =====================================================================================
__device__ __forceinline__ void issueA2(
    const u16* __restrict__ Ab, int lda, int m0, int t, int h, u16* smem) {
    int tid = threadIdx.x;
    u16* base = smem + (t & 1) * 16384 + h * 8192;
#pragma unroll
    for (int l = 0; l < 2; ++l) {
        int c = l * 512 + tid;
        int rho = c >> 3, p = c & 7;
        int kc = p ^ (rho & 7);
        int r = ((rho >> 6) << 7) | (h << 6) | (rho & 63);
        load_lds16(Ab + (size_t)(m0 + r) * lda + (t << 6) + (kc << 3), base + (c << 3));
    }
}
__device__ __forceinline__ void issueB2(
    const u16* __restrict__ Bb, int ldb, int n0, int t, int h, u16* smem) {
    int tid = threadIdx.x;
    u16* base = smem + 32768 + (t & 1) * 16384 + h * 8192;
#pragma unroll
    for (int l = 0; l < 2; ++l) {
        int c = l * 512 + tid;
        int rho = c >> 3, p = c & 7;
        int kc = p ^ (rho & 7);
        int r = ((rho >> 5) << 6) | (h << 5) | (rho & 31);
        load_lds16(Bb + (size_t)(n0 + r) * ldb + (t << 6) + (kc << 3), base + (c << 3));
    }
}

__device__ __forceinline__ void gemm256x256(
    const u16* __restrict__ Ab, const u16* __restrict__ Bb, int K, int lda, int ldb,
    int m0, int n0, u16* smem, floatx4 (&acc)[8][4]) {
    int tid = threadIdx.x;
    int lane = tid & 63, wave = tid >> 6;
    int quad = lane >> 4, lrow = lane & 15;
    int wrow = wave >> 2, wcol = wave & 3;
    int nt = K >> 6;
    // prologue: stage tile 0 (8 load instrs/wave in flight)
    issueA2(Ab, lda, m0, 0, 0, smem);
    issueA2(Ab, lda, m0, 0, 1, smem);
    issueB2(Bb, ldb, n0, 0, 0, smem);
    issueB2(Bb, ldb, n0, 0, 1, smem);
    for (int t = 0; t < nt; ++t) {
        int slot = t & 1;
        BARRIER;   // B1: all waves' tile-(t-1) reads done -> its slot is writable
        if (t + 1 < nt) {
            issueA2(Ab, lda, m0, t + 1, 0, smem);
            issueA2(Ab, lda, m0, t + 1, 1, smem);
            issueB2(Bb, ldb, n0, t + 1, 0, smem);
            issueB2(Bb, ldb, n0, t + 1, 1, smem);
            asm volatile("s_waitcnt vmcnt(8)" ::: "memory");   // own tile-t loads done
        } else {
            asm volatile("s_waitcnt vmcnt(0)" ::: "memory");
        }
        BARRIER;   // B2: tile t visible to all waves
        const u16* Ah = smem + slot * 16384;
        const u16* Bh = smem + 32768 + slot * 16384;
        // --- free-scheduled compute region: 24 ds_read_b128 + 64 MFMA ---
        short8 bf[2][4];
#pragma unroll
        for (int qn = 0; qn < 2; ++qn)
#pragma unroll
            for (int ks = 0; ks < 2; ++ks)
#pragma unroll
                for (int j = 0; j < 2; ++j) {
                    int rho = wcol * 32 + j * 16 + lrow;
                    int p = (ks * 4 + quad) ^ (lrow & 7);
                    bf[qn][ks * 2 + j] = *(const short8*)&Bh[qn * 8192 + (rho << 6) + (p << 3)];
                }
#pragma unroll
        for (int qm = 0; qm < 2; ++qm) {
            short8 af[8];
#pragma unroll
            for (int ks = 0; ks < 2; ++ks)
#pragma unroll
                for (int i = 0; i < 4; ++i) {
                    int rho = wrow * 64 + i * 16 + lrow;
                    int p = (ks * 4 + quad) ^ (lrow & 7);
                    af[ks * 4 + i] = *(const short8*)&Ah[qm * 8192 + (rho << 6) + (p << 3)];
                }
#pragma unroll
            for (int ks = 0; ks < 2; ++ks)
#pragma unroll
                for (int i = 0; i < 4; ++i)
#pragma unroll
                    for (int qn = 0; qn < 2; ++qn)
#pragma unroll
                        for (int j = 0; j < 2; ++j)
                            acc[qm * 4 + i][qn * 2 + j] = __builtin_amdgcn_mfma_f32_16x16x32_bf16(
                                af[ks * 4 + i], bf[qn][ks * 2 + j], acc[qm * 4 + i][qn * 2 + j], 0, 0, 0);
        }
    }
}

// =====================================================================================
// 256x128x64 8-wave core (512 thr): per-wave 64x64, acc[4][4].
// LDS 96KB: A 2 slots x (256 x 64 u16) + B 2 slots x 2 halves x (64 x 64 u16).
// Same 2-barrier counted-vmcnt K-loop; 16 ds_read_b128 + 32 MFMA per tile, free-scheduled.
// =====================================================================================
__device__ __forceinline__ void issueA4(
    const u16* __restrict__ Ab, int lda, int m0, int t, u16* smem) {
    int tid = threadIdx.x;
    u16* base = smem + (t & 1) * 16384;
#pragma unroll
    for (int l = 0; l < 4; ++l) {
        int c = l * 512 + tid;
        int rho = c >> 3, p = c & 7;
        int kc = p ^ (rho & 7);
        load_lds16(Ab + (size_t)(m0 + rho) * lda + (t << 6) + (kc << 3), base + (c << 3));
    }
}
__device__ __forceinline__ void issueB4(
    const u16* __restrict__ Bb, int ldb, int n0, int t, int h, u16* smem) {
    int tid = threadIdx.x;
    u16* base = smem + 32768 + (t & 1) * 8192 + h * 4096;
    int rho = tid >> 3, p = tid & 7;
    int kc = p ^ (rho & 7);
    int r = ((rho >> 5) << 6) | (h << 5) | (rho & 31);
    load_lds16(Bb + (size_t)(n0 + r) * ldb + (t << 6) + (kc << 3), base + (tid << 3));
}

__device__ __forceinline__ void gemm256x128(
    const u16* __restrict__ Ab, const u16* __restrict__ Bb, int K, int lda, int ldb,
    int m0, int n0, u16* smem, floatx4 (&acc)[4][4]) {
    int tid = threadIdx.x;
    int lane = tid & 63, wave = tid >> 6;
    int quad = lane >> 4, lrow = lane & 15;
    int wrow = wave >> 1, wcol = wave & 1;
    int nt = K >> 6;
    // prologue: stage tile 0 (6 load instrs/wave)
    issueA4(Ab, lda, m0, 0, smem);
    issueB4(Bb, ldb, n0, 0, 0, smem);
    issueB4(Bb, ldb, n0, 0, 1, smem);
    for (int t = 0; t < nt; ++t) {
        int slot = t & 1;
        BARRIER;   // B1
        if (t + 1 < nt) {
            issueA4(Ab, lda, m0, t + 1, smem);
            issueB4(Bb, ldb, n0, t + 1, 0, smem);
            issueB4(Bb, ldb, n0, t + 1, 1, smem);
            asm volatile("s_waitcnt vmcnt(6)" ::: "memory");
        } else {
            asm volatile("s_waitcnt vmcnt(0)" ::: "memory");
        }
        BARRIER;   // B2
        const u16* Ah = smem + slot * 16384;
        const u16* Bh = smem + 32768 + slot * 8192;
        // --- free-scheduled compute region: 16 ds_read_b128 + 32 MFMA ---
        short8 bf[2][4];
#pragma unroll
        for (int qn = 0; qn < 2; ++qn)
#pragma unroll
            for (int ks = 0; ks < 2; ++ks)
#pragma unroll
                for (int j = 0; j < 2; ++j) {
                    int rho = wcol * 32 + j * 16 + lrow;
                    int p = (ks * 4 + quad) ^ (lrow & 7);
                    bf[qn][ks * 2 + j] = *(const short8*)&Bh[qn * 4096 + (rho << 6) + (p << 3)];
                }
        short8 af[8];
#pragma unroll
        for (int ks = 0; ks < 2; ++ks)
#pragma unroll
            for (int i = 0; i < 4; ++i) {
                int rho = wrow * 64 + i * 16 + lrow;
                int p = (ks * 4 + quad) ^ (lrow & 7);
                af[ks * 4 + i] = *(const short8*)&Ah[(rho << 6) + (p << 3)];
            }
#pragma unroll
        for (int ks = 0; ks < 2; ++ks)
#pragma unroll
            for (int i = 0; i < 4; ++i)
#pragma unroll
                for (int qn = 0; qn < 2; ++qn)
#pragma unroll
                    for (int j = 0; j < 2; ++j)
                        acc[i][qn * 2 + j] = __builtin_amdgcn_mfma_f32_16x16x32_bf16(
                            af[ks * 4 + i], bf[qn][ks * 2 + j], acc[i][qn * 2 + j], 0, 0, 0);
    }
}

#define ACC_INIT84 floatx4 acc[8][4]; \
    _Pragma("unroll") for (int i = 0; i < 8; ++i) \
    _Pragma("unroll") for (int j = 0; j < 4; ++j) acc[i][j] = (floatx4){0.f, 0.f, 0.f, 0.f};

#define ACC_INIT44 floatx4 acc[4][4]; \
    _Pragma("unroll") for (int i = 0; i < 4; ++i) \
    _Pragma("unroll") for (int j = 0; j < 4; ++j) acc[i][j] = (floatx4){0.f, 0.f, 0.f, 0.f};

// ================= D2: GN apply+transpose (z<16) + Wpv GEMM (z==16) =================
#define TSTR 66
__global__ __launch_bounds__(256) void gn_wpv_kernel(
    const float* __restrict__ x, const float* __restrict__ gamma, const float* __restrict__ beta,
    const float* __restrict__ stats, u16* __restrict__ hT,
    const u16* __restrict__ wproj_bf, const u16* __restrict__ wv_t, u16* __restrict__ wmega) {
    __shared__ u16 smem[2 * 128 * 64];
    int tid = threadIdx.x;
    if (blockIdx.z == 16) {  // Wpv = wproj_bf . wv_t^T -> wmega rows 1024..1535
        if (blockIdx.x >= 4 || blockIdx.y >= 4) return;
        int m0 = blockIdx.y << 7, n0 = blockIdx.x << 7;
        ACC_INIT;
        gemm_core_sb(wproj_bf, wv_t, CDIM, CDIM, CDIM, m0, n0, smem, smem + 128 * 64, acc);
        EPILOG_IDX;
#pragma unroll
        for (int i = 0; i < 4; ++i)
#pragma unroll
            for (int j = 0; j < 4; ++j)
#pragma unroll
                for (int r = 0; r < 4; ++r) {
                    int R = m0 + wm + i * 16 + (quad << 2) + r;
                    int Cc = n0 + wn + j * 16 + lrow;
                    wmega[(size_t)(1024 + R) * CDIM + Cc] = f2bf(acc[i][j][r]);
                }
        return;
    }
    u16* t = smem;
    int b = blockIdx.z, c0 = blockIdx.y << 6, n0 = blockIdx.x << 6;
    const float* xb = x + ((size_t)b * CDIM + c0) * NSPAT + n0;
#pragma unroll
    for (int p = 0; p < 4; ++p) {
        int cl = p * 16 + (tid >> 4);
        int nl = (tid & 15) << 2;
        int c = c0 + cl;
        int bg = b * NGROUP + (c >> 6);
        float ga = gamma[c] * stats[bg * 2 + 1];
        float be = beta[c] - stats[bg * 2] * ga;
        float4 v = *(const float4*)(xb + (size_t)cl * NSPAT + nl);
        u16* dst = &t[cl * TSTR + nl];
        dst[0] = f2bf(v.x * ga + be);
        dst[1] = f2bf(v.y * ga + be);
        dst[2] = f2bf(v.z * ga + be);
        dst[3] = f2bf(v.w * ga + be);
    }
    __syncthreads();
    u16* hb = hT + ((size_t)b * NSPAT + n0) * CDIM + c0;
#pragma unroll
    for (int p = 0; p < 4; ++p) {
        int nl = p * 16 + (tid >> 4);
        int cl4 = (tid & 15) << 2;
        ushort4 o;
        o.x = t[(cl4 + 0) * TSTR + nl];
        o.y = t[(cl4 + 1) * TSTR + nl];
        o.z = t[(cl4 + 2) * TSTR + nl];
        o.w = t[(cl4 + 3) * TSTR + nl];
        *(ushort4*)(hb + (size_t)nl * CDIM + cl4) = o;
    }
}

// ================= D3: qkv-mega: [q;k;WV] = wmega . h + [b_qkv(qk); bpv] =================
// grid (BATCH, 4, 6), 512 thr: y = n-tile(256), z = m-tile(256); z<4 -> q,k; z>=4 -> WV.
__global__ __launch_bounds__(512, 2) void qkv_kernel(
    const u16* __restrict__ wmega, const u16* __restrict__ hT,
    const float* __restrict__ b_qkv, const float* __restrict__ bpv,
    u16* __restrict__ qkT, u16* __restrict__ WV) {
    extern __shared__ u16 smem[];
    int z = blockIdx.x;
    int n0 = blockIdx.y << 8;
    int m0 = blockIdx.z << 8;
    const u16* Bb = hT + (size_t)z * CDIM * NSPAT;
    ACC_INIT84;
    gemm256x256(wmega, Bb, CDIM, CDIM, CDIM, m0, n0, smem, acc);
    int lane = threadIdx.x & 63, wave = threadIdx.x >> 6;
    int quad = lane >> 4, lrow = lane & 15;
    int wrow = wave >> 2, wcol = wave & 3;
    if (blockIdx.z < 4) {  // q,k rows: transposed packed store to qkT[n][o], ldc=1024
        u16* qk = qkT + (size_t)z * NSPAT * NSPAT;
#pragma unroll
        for (int mf = 0; mf < 8; ++mf) {
            int R0 = m0 + wrow * 128 + mf * 16 + (quad << 2);
            float4 bv = *(const float4*)&b_qkv[R0];
#pragma unroll
            for (int nf = 0; nf < 4; ++nf) {
                int Cc = n0 + wcol * 64 + nf * 16 + lrow;
                uint2 u;
                u.x = f2bf2(acc[mf][nf][0] + bv.x, acc[mf][nf][1] + bv.y);
                u.y = f2bf2(acc[mf][nf][2] + bv.z, acc[mf][nf][3] + bv.w);
                *(uint2*)&qk[(size_t)Cc * NSPAT + R0] = u;
            }
        }
    } else {  // WV rows: natural store WV[o][n] + bpv
        u16* Wp = WV + (size_t)z * CDIM * NSPAT;
#pragma unroll
        for (int mf = 0; mf < 8; ++mf) {
            int R = m0 - 1024 + wrow * 128 + mf * 16 + (quad << 2);
            float4 pv = *(const float4*)&bpv[R];
#pragma unroll
            for (int nf = 0; nf < 4; ++nf) {
                int Cc = n0 + wcol * 64 + nf * 16 + lrow;
                Wp[(size_t)(R + 0) * NSPAT + Cc] = f2bf(acc[mf][nf][0] + pv.x);
                Wp[(size_t)(R + 1) * NSPAT + Cc] = f2bf(acc[mf][nf][1] + pv.y);
                Wp[(size_t)(R + 2) * NSPAT + Cc] = f2bf(acc[mf][nf][2] + pv.z);
                Wp[(size_t)(R + 3) * NSPAT + Cc] = f2bf(acc[mf][nf][3] + pv.w);
            }
        }
    }
}

// ================= D4: scores (swapped operands): D[j][i] = k_j . q_i =================
// grid (BATCH, 4, 4), 512 thr: y = i-tile(256), z = j-tile(256).
__global__ __launch_bounds__(512, 2) void scores_kernel(
    const u16* __restrict__ qkT, u16* __restrict__ P, float* __restrict__ lsums, float scale) {
    extern __shared__ u16 smem[];
    int z = blockIdx.x;
    int n0 = blockIdx.y << 8;                // i tile (N-dim)
    int m0 = blockIdx.z << 8;                // j tile (M-dim)
    const u16* qb = qkT + (size_t)z * NSPAT * NSPAT;
    ACC_INIT84;
    gemm256x256(qb + CDIM, qb, CDIM, NSPAT, NSPAT, m0, n0, smem, acc);
    int lane = threadIdx.x & 63, wave = threadIdx.x >> 6;
    int quad = lane >> 4, lrow = lane & 15;
    int wrow = wave >> 2, wcol = wave & 3;
    u16* Pp = P + (size_t)z * NSPAT * NSPAT;
    float* ls = lsums + (size_t)z * NSPAT;
#pragma unroll
    for (int nf = 0; nf < 4; ++nf) {
        int Ci = n0 + wcol * 64 + nf * 16 + lrow;    // i (column of D)
        float part = 0.f;
#pragma unroll
        for (int mf = 0; mf < 8; ++mf) {
            int Rj0 = m0 + wrow * 128 + mf * 16 + (quad << 2);   // j rows, 4 consecutive
            float e0 = __expf(acc[mf][nf][0] * scale);
            float e1 = __expf(acc[mf][nf][1] * scale);
            float e2 = __expf(acc[mf][nf][2] * scale);
            float e3 = __expf(acc[mf][nf][3] * scale);
            part += (e0 + e1) + (e2 + e3);
            uint2 u;
            u.x = f2bf2(e0, e1);
            u.y = f2bf2(e2, e3);
            *(uint2*)&Pp[(size_t)Ci * NSPAT + Rj0] = u;
        }
        part += __shfl_xor(part, 16);
        part += __shfl_xor(part, 32);
        if (lane < 16) atomicAdd(&ls[Ci], part);
    }
}

// ================= D5: final (swapped operands): D[i][o] = P_i . WV_o =================
// grid (BATCH, 4, 4), 512 thr: y = o-tile(128), z = i-tile(256).
__global__ __launch_bounds__(512, 2) void final_kernel(
    const u16* __restrict__ WV, const u16* __restrict__ P, const float* __restrict__ lsums,
    const float* __restrict__ bias, const float* __restrict__ x, float* __restrict__ out) {
    extern __shared__ u16 smem[];
    int z = blockIdx.x;
    int n0 = blockIdx.y << 7;                // o tile (N-dim, 4 tiles of 128)
    int m0 = blockIdx.z << 8;                // i tile (M-dim, 4 tiles of 256)
    const u16* Pb = P + (size_t)z * NSPAT * NSPAT;
    const u16* WVb = WV + (size_t)z * CDIM * NSPAT;
    ACC_INIT44;
    gemm256x128(Pb, WVb, NSPAT, NSPAT, NSPAT, m0, n0, smem, acc);
    int lane = threadIdx.x & 63, wave = threadIdx.x >> 6;
    int quad = lane >> 4, lrow = lane & 15;
    int wrow = wave >> 1, wcol = wave & 1;
    float* Op = out + (size_t)z * CDIM * NSPAT;
    const float* xr = x + (size_t)z * CDIM * NSPAT;
    const float* li = lsums + (size_t)z * NSPAT;
#pragma unroll
    for (int mf = 0; mf < 4; ++mf) {
        int Ri0 = m0 + wrow * 64 + mf * 16 + (quad << 2);        // i, 4 consecutive
        float4 lv = *(const float4*)&li[Ri0];
        float s0 = __builtin_amdgcn_rcpf(lv.x);
        float s1 = __builtin_amdgcn_rcpf(lv.y);
        float s2 = __builtin_amdgcn_rcpf(lv.z);
        float s3 = __builtin_amdgcn_rcpf(lv.w);
#pragma unroll
        for (int nf = 0; nf < 4; ++nf) {
            int Co = n0 + wcol * 64 + nf * 16 + lrow;            // o
            float bv = bias[Co];
            size_t off = (size_t)Co * NSPAT + Ri0;
            float4 xv = *(const float4*)&xr[off];
            float4 o;
            o.x = acc[mf][nf][0] * s0 + bv + xv.x;
            o.y = acc[mf][nf][1] * s1 + bv + xv.y;
            o.z = acc[mf][nf][2] * s2 + bv + xv.z;
            o.w = acc[mf][nf][3] * s3 + bv + xv.w;
            *(float4*)&Op[off] = o;
        }
    }
}

// ================= launch =================
extern "C" void kernel_launch(void* const* d_in, const int* in_sizes, int n_in,
                              void* d_out, int out_size, void* d_ws, size_t ws_size,
                              hipStream_t stream) {
    const float* x      = (const float*)d_in[0];
    const float* gamma  = (const float*)d_in[1];
    const float* beta   = (const float*)d_in[2];
    const float* w_qkv  = (const float*)d_in[3];
    const float* b_qkv  = (const float*)d_in[4];
    const float* w_proj = (const float*)d_in[5];
    const float* b_proj = (const float*)d_in[6];
    float* out = (float*)d_out;

    const size_t CN = (size_t)CDIM * NSPAT;   // 524288
    const size_t NN = (size_t)NSPAT * NSPAT;  // 1048576
    const float SCALE = 0.044194173824159216f;
    const int LDS_BIG = 131072;   // 256x256 core: 2x(32KB A + 32KB B)
    const int LDS_MED = 98304;    // 256x128 core: 2x(32KB A + 16KB B)

    // One-time opt-in for >64KB dynamic LDS (graph-capture-safe: no alloc/sync).
    static bool lds_attr_done = false;
    if (!lds_attr_done) {
        hipFuncSetAttribute((const void*)qkv_kernel,
                            hipFuncAttributeMaxDynamicSharedMemorySize, LDS_BIG);
        hipFuncSetAttribute((const void*)scores_kernel,
                            hipFuncAttributeMaxDynamicSharedMemorySize, LDS_BIG);
        hipFuncSetAttribute((const void*)final_kernel,
                            hipFuncAttributeMaxDynamicSharedMemorySize, LDS_MED);
        lds_attr_done = true;
    }

    char* ws = (char*)d_ws;
    float* stats   = (float*)ws;                              // 1 KB
    float* bpv     = (float*)(ws + 1024);                     // 2 KB
    u16* wmega     = (u16*)(ws + 4096);                       // [Wq;Wk;Wpv] 1536x512 bf16
    u16* wproj_bf  = wmega + (size_t)3 * CDIM * CDIM;         // 0.5 MB
    u16* wv_t      = wproj_bf + (size_t)CDIM * CDIM;          // 0.5 MB
    u16* hT        = wv_t + (size_t)CDIM * CDIM;              // 16.8 MB [n][c]
    u16* qkT       = hT + BATCH * CN;                         // 33.5 MB [n][q,k:1024]
    u16* WV        = qkT + BATCH * NN;                        // 16.8 MB [o][n]
    u16* P         = WV + BATCH * CN;                         // 33.5 MB [i][j] unnorm
    float* lsums   = (float*)(P + BATCH * NN);                // 64 KB

    prep_kernel<<<984, 256, 0, stream>>>(
        w_qkv, w_proj, b_qkv, x, wmega, wproj_bf, wv_t, stats, lsums, bpv);

    gn_wpv_kernel<<<dim3(16, 8, 17), 256, 0, stream>>>(
        x, gamma, beta, stats, hT, wproj_bf, wv_t, wmega);

    qkv_kernel<<<dim3(BATCH, 4, 6), 512, LDS_BIG, stream>>>(
        wmega, hT, b_qkv, bpv, qkT, WV);

    scores_kernel<<<dim3(BATCH, 4, 4), 512, LDS_BIG, stream>>>(qkT, P, lsums, SCALE);

    final_kernel<<<dim3(BATCH, 4, 4), 512, LDS_MED, stream>>>(WV, P, lsums, b_proj, x, out);
}